// Round 2
// baseline (613.444 us; speedup 1.0000x reference)
//
#include <hip/hip_runtime.h>

typedef unsigned short u16;
typedef __attribute__((ext_vector_type(8))) short short8x;
typedef __attribute__((ext_vector_type(4))) float f32x4;

#define B_ 2
#define L_ 2048
#define HID_ 2048
#define H_ 8
#define HD_ 256

__device__ __forceinline__ u16 f2bf(float f) {
  union { float f; unsigned u; } v; v.f = f;
  unsigned r = v.u + 0x7FFFu + ((v.u >> 16) & 1u);
  return (u16)(r >> 16);
}
__device__ __forceinline__ float bf2f(u16 u) {
  union { unsigned u; float f; } v; v.u = ((unsigned)u) << 16;
  return v.f;
}

// x fp32 -> bf16, same layout. grid = nelem/4/256
__global__ __launch_bounds__(256) void cvt_x_kernel(const float4* __restrict__ in,
                                                    u16* __restrict__ out) {
  int idx = blockIdx.x * 256 + threadIdx.x;
  float4 v = in[idx];
  u16* o = out + (size_t)idx * 4;
  o[0] = f2bf(v.x); o[1] = f2bf(v.y); o[2] = f2bf(v.z); o[3] = f2bf(v.w);
}

// W fp32 [K][N] -> Wt bf16 [N][K]. grid (N/32, K/32), block (32,8)
__global__ __launch_bounds__(256) void cvt_wt_kernel(const float* __restrict__ W,
                                                     u16* __restrict__ Wt, int K, int N) {
  __shared__ float tile[32][33];
  int n0 = blockIdx.x * 32, k0 = blockIdx.y * 32;
  int tx = threadIdx.x, ty = threadIdx.y;
#pragma unroll
  for (int i = 0; i < 32; i += 8)
    tile[ty + i][tx] = W[(size_t)(k0 + ty + i) * N + n0 + tx];
  __syncthreads();
#pragma unroll
  for (int i = 0; i < 32; i += 8)
    Wt[(size_t)(n0 + ty + i) * K + k0 + tx] = f2bf(tile[tx][ty + i]);
}

// RoPE + head-permute. in: bf16 [B*L][in_stride] (+off); out: bf16 [(b*nh+h)*L + l][256]
__global__ __launch_bounds__(256) void rope_kernel(const u16* __restrict__ in,
                                                   u16* __restrict__ out, int nh_shift,
                                                   int in_stride, int in_off) {
  int idx = blockIdx.x * 256 + threadIdx.x;
  int nh = 1 << nh_shift;
  int d = idx & 127;
  int t = idx >> 7;
  int h = t & (nh - 1);
  int row = t >> nh_shift;  // b*L + l
  int l = row & (L_ - 1);
  int b = row >> 11;
  size_t ibase = (size_t)row * in_stride + in_off + h * 256 + d;
  float x1 = bf2f(in[ibase]);
  float x2 = bf2f(in[ibase + 128]);
  float f = exp2f(-(float)d * (13.287712379549449f / 128.0f));
  float ang = (float)l * f;
  float s, c;
  sincosf(ang, &s, &c);
  size_t obase = ((size_t)(b * nh + h) * L_ + l) * 256 + d;
  out[obase] = f2bf(x1 * c - x2 * s);
  out[obase + 128] = f2bf(x2 * c + x1 * s);
}

// kvproj bf16 [B*L][512] (V at col off 256) -> vt bf16 [(b*256+d)][L]
__global__ __launch_bounds__(256) void vt_kernel(const u16* __restrict__ kvproj,
                                                 u16* __restrict__ vt) {
  int idx = blockIdx.x * 256 + threadIdx.x;  // = (b*256+d)*2048 + l
  int l = idx & 2047;
  int d = (idx >> 11) & 255;
  int b = idx >> 19;
  vt[idx] = kvproj[((size_t)b * 2048 + l) * 512 + 256 + d];
}

// C[M][N] = A[M][K] @ Bt[N][K]^T, bf16 in, fp32 acc, bf16 or fp32 out.
// 128x128 tile, BK=32, 4 waves in 2x2, each wave 64x64 (4x4 fragments).
template <int F32OUT>
__global__ __launch_bounds__(256) void gemm_bt_kernel(const u16* __restrict__ A,
                                                      const u16* __restrict__ Bt,
                                                      void* __restrict__ Cv,
                                                      int M, int N, int K) {
  __shared__ u16 As[128 * 32];
  __shared__ u16 Bs[128 * 32];
  const int tid = threadIdx.x;
  const int lane = tid & 63;
  const int w = tid >> 6;
  const int wr = w >> 1, wc = w & 1;
  const int m0 = blockIdx.y * 128, n0 = blockIdx.x * 128;
  const int l15 = lane & 15, l4 = lane >> 4;
  f32x4 acc[4][4] = {};
  for (int kt = 0; kt < K; kt += 32) {
#pragma unroll
    for (int i = 0; i < 2; ++i) {
      int c = tid + i * 256;
      int row = c >> 2, cin = c & 3;
      *(float4*)(&As[row * 32 + cin * 8]) =
          *(const float4*)(A + (size_t)(m0 + row) * K + kt + cin * 8);
      *(float4*)(&Bs[row * 32 + cin * 8]) =
          *(const float4*)(Bt + (size_t)(n0 + row) * K + kt + cin * 8);
    }
    __syncthreads();
    short8x a[4], b[4];
#pragma unroll
    for (int m = 0; m < 4; ++m)
      a[m] = *(const short8x*)(&As[(wr * 64 + m * 16 + l15) * 32 + l4 * 8]);
#pragma unroll
    for (int n = 0; n < 4; ++n)
      b[n] = *(const short8x*)(&Bs[(wc * 64 + n * 16 + l15) * 32 + l4 * 8]);
#pragma unroll
    for (int m = 0; m < 4; ++m)
#pragma unroll
      for (int n = 0; n < 4; ++n)
        acc[m][n] = __builtin_amdgcn_mfma_f32_16x16x32_bf16(a[m], b[n], acc[m][n], 0, 0, 0);
    __syncthreads();
  }
#pragma unroll
  for (int m = 0; m < 4; ++m) {
#pragma unroll
    for (int n = 0; n < 4; ++n) {
      int gcol = n0 + wc * 64 + n * 16 + l15;
#pragma unroll
      for (int r = 0; r < 4; ++r) {
        int grow = m0 + wr * 64 + m * 16 + l4 * 4 + r;
        if (F32OUT)
          ((float*)Cv)[(size_t)grow * N + gcol] = acc[m][n][r];
        else
          ((u16*)Cv)[(size_t)grow * N + gcol] = f2bf(acc[m][n][r]);
      }
    }
  }
}

// Flash attention v2. qb: [B*H][L][256], kb: [B][L][256], vt: [B][256][L],
// attn_o: [B*L][H*256].
// Block = 256 threads (4 waves x 16 q-rows, QBLK=64), KVBLK=64.
// grid = (32, B*H); qt = 31 - blockIdx.x (heavy blocks dispatched first).
// K/V^T staged in XOR-swizzled LDS; next tile reg-staged async (T14).
__global__ __launch_bounds__(256, 2) void flash_kernel(const u16* __restrict__ qb,
                                                       const u16* __restrict__ kb,
                                                       const u16* __restrict__ vt,
                                                       u16* __restrict__ attn_o) {
  __shared__ u16 Ks[64 * 256];    // [row k][d], byte ^= (row&7)<<4
  __shared__ u16 Vts[256 * 64];   // [row d][k], byte ^= (d&7)<<4
  __shared__ u16 Ps[4 * 16 * 72]; // per-wave [16][64] padded to 72
  const int qt = 31 - (int)blockIdx.x;
  const int bh = blockIdx.y;
  const int b = bh >> 3;
  const int h = bh & 7;
  const int tid = threadIdx.x, lane = tid & 63, w = tid >> 6;
  const int l15 = lane & 15, l4 = lane >> 4;
  const int q0 = qt * 64;

  // Q fragments: wave w owns rows q0 + w*16 .. +15
  const u16* qrow = qb + ((size_t)bh * L_ + q0 + w * 16 + l15) * 256;
  short8x qf[8];
#pragma unroll
  for (int kc = 0; kc < 8; ++kc)
    qf[kc] = *(const short8x*)(qrow + kc * 32 + l4 * 8);

  f32x4 o[16] = {};
  float mrow[4] = {-3e38f, -3e38f, -3e38f, -3e38f};
  float srow[4] = {0.f, 0.f, 0.f, 0.f};

  const u16* kbase = kb + (size_t)b * (L_ * 256);
  const u16* vbase = vt + (size_t)b * (256 * L_);
  float4 kreg[8], vreg[8];
  const int krow = tid >> 5, kcol = tid & 31;        // chunk ids for i-th pass add 8 rows / 32 d
  const int vrow = tid >> 3, vcol = tid & 7;

#define LOAD_KV(t)                                                                   \
  {                                                                                  \
    _Pragma("unroll") for (int i = 0; i < 8; ++i) {                                  \
      kreg[i] = *(const float4*)(kbase + ((size_t)((t) * 64 + krow + i * 8)) * 256 + \
                                 kcol * 8);                                          \
      vreg[i] = *(const float4*)(vbase + (size_t)(vrow + i * 32) * L_ + (t) * 64 +   \
                                 vcol * 8);                                          \
    }                                                                                \
  }
#define WRITE_KV()                                                                       \
  {                                                                                      \
    _Pragma("unroll") for (int i = 0; i < 8; ++i) {                                      \
      int rk = krow + i * 8;                                                             \
      *(float4*)((char*)Ks + (((rk * 256 + kcol * 8) * 2) ^ ((rk & 7) << 4))) = kreg[i]; \
      int rd = vrow + i * 32;                                                            \
      *(float4*)((char*)Vts + (((rd * 64 + vcol * 8) * 2) ^ ((rd & 7) << 4))) = vreg[i]; \
    }                                                                                    \
  }

  LOAD_KV(0);
  WRITE_KV();
  __syncthreads();

  for (int t = 0; t <= qt; ++t) {
    if (t < qt) LOAD_KV(t + 1);  // async: regs land under compute
    // S = Q K^T : 16 rows x 64 cols
    f32x4 sacc[4] = {};
#pragma unroll
    for (int kc = 0; kc < 8; ++kc)
#pragma unroll
      for (int n = 0; n < 4; ++n) {
        int row = n * 16 + l15;
        short8x kf = *(const short8x*)((char*)Ks +
            (((row * 256 + kc * 32 + l4 * 8) * 2) ^ ((row & 7) << 4)));
        sacc[n] = __builtin_amdgcn_mfma_f32_16x16x32_bf16(qf[kc], kf, sacc[n], 0, 0, 0);
      }
    float p[4][4];
    const bool dm = (t == qt);
#pragma unroll
    for (int n = 0; n < 4; ++n) {
      int jg = t * 64 + n * 16 + l15;
#pragma unroll
      for (int r = 0; r < 4; ++r) {
        float v = sacc[n][r] * 0.0625f;  // HD^-0.5
        if (dm && (jg > q0 + w * 16 + l4 * 4 + r)) v = -1e30f;
        p[n][r] = v;
      }
    }
    float alpha[4];
#pragma unroll
    for (int r = 0; r < 4; ++r) {
      float rm = fmaxf(fmaxf(p[0][r], p[1][r]), fmaxf(p[2][r], p[3][r]));
#pragma unroll
      for (int off = 1; off < 16; off <<= 1)
        rm = fmaxf(rm, __shfl_xor(rm, off));
      float mn = fmaxf(mrow[r], rm);
      alpha[r] = __expf(mrow[r] - mn);
      mrow[r] = mn;
      float rs = 0.f;
#pragma unroll
      for (int n = 0; n < 4; ++n) {
        p[n][r] = __expf(p[n][r] - mn);
        rs += p[n][r];
      }
#pragma unroll
      for (int off = 1; off < 16; off <<= 1)
        rs += __shfl_xor(rs, off);
      srow[r] = srow[r] * alpha[r] + rs;
    }
#pragma unroll
    for (int ff = 0; ff < 16; ++ff) {
      o[ff][0] *= alpha[0]; o[ff][1] *= alpha[1];
      o[ff][2] *= alpha[2]; o[ff][3] *= alpha[3];
    }
    // P (C-layout) -> LDS -> A-layout fragments
#pragma unroll
    for (int n = 0; n < 4; ++n)
#pragma unroll
      for (int r = 0; r < 4; ++r)
        Ps[w * 1152 + (l4 * 4 + r) * 72 + n * 16 + l15] = f2bf(p[n][r]);
    asm volatile("s_waitcnt lgkmcnt(0)" ::: "memory");
    short8x paf[2];
#pragma unroll
    for (int kc2 = 0; kc2 < 2; ++kc2)
      paf[kc2] = *(const short8x*)(&Ps[w * 1152 + l15 * 72 + kc2 * 32 + l4 * 8]);
    // O += P V : contraction over j=64
#pragma unroll
    for (int kc2 = 0; kc2 < 2; ++kc2)
#pragma unroll
      for (int ff = 0; ff < 16; ++ff) {
        int rd = ff * 16 + l15;
        short8x vf = *(const short8x*)((char*)Vts +
            (((rd * 64 + kc2 * 32 + l4 * 8) * 2) ^ ((rd & 7) << 4)));
        o[ff] = __builtin_amdgcn_mfma_f32_16x16x32_bf16(paf[kc2], vf, o[ff], 0, 0, 0);
      }
    __syncthreads();
    if (t < qt) WRITE_KV();
    __syncthreads();
  }
#pragma unroll
  for (int r = 0; r < 4; ++r) {
    float inv = 1.0f / srow[r];
    int grow = q0 + w * 16 + l4 * 4 + r;
    size_t base = ((size_t)b * L_ + grow) * (size_t)(H_ * HD_) + h * 256;
#pragma unroll
    for (int ff = 0; ff < 16; ++ff)
      attn_o[base + ff * 16 + l15] = f2bf(o[ff][r] * inv);
  }
#undef LOAD_KV
#undef WRITE_KV
}

extern "C" void kernel_launch(void* const* d_in, const int* in_sizes, int n_in,
                              void* d_out, int out_size, void* d_ws, size_t ws_size,
                              hipStream_t stream) {
  const float* x  = (const float*)d_in[0];
  const float* Wq = (const float*)d_in[1];
  const float* Wk = (const float*)d_in[2];
  const float* Wv = (const float*)d_in[3];
  const float* Wo = (const float*)d_in[4];
  // d_in[5] = additive causal mask: semantics reproduced analytically, not read.
  float* out = (float*)d_out;
  char* ws = (char*)d_ws;
  size_t off = 0;
  auto alloc = [&](size_t bytes) {
    void* p = ws + off;
    off = (off + bytes + 255) & ~(size_t)255;
    return p;
  };
  u16* wq_t   = (u16*)alloc(2048ull * 2048 * 2);  // [2048][2048] = Wq^T
  u16* wkv_t  = (u16*)alloc(512ull * 2048 * 2);   // rows 0..255 = Wk^T, 256..511 = Wv^T
  u16* wo_t   = (u16*)alloc(2048ull * 2048 * 2);
  u16* xbf    = (u16*)alloc(4096ull * 2048 * 2);  // reused as roped Q
  u16* qproj  = (u16*)alloc(4096ull * 2048 * 2);  // reused as attn output
  u16* kvproj = (u16*)alloc(4096ull * 512 * 2);   // [B*L][512]: K | V
  u16* kb     = (u16*)alloc(4096ull * 256 * 2);
  u16* vtb    = (u16*)alloc(4096ull * 256 * 2);
  u16* qbuf   = xbf;    // alias: x_bf dead after KV projection
  u16* attn_o = qproj;  // alias: qproj dead after rope_q

  cvt_x_kernel<<<8192, 256, 0, stream>>>((const float4*)x, xbf);
  cvt_wt_kernel<<<dim3(64, 64), dim3(32, 8), 0, stream>>>(Wq, wq_t, 2048, 2048);
  cvt_wt_kernel<<<dim3(8, 64),  dim3(32, 8), 0, stream>>>(Wk, wkv_t, 2048, 256);
  cvt_wt_kernel<<<dim3(8, 64),  dim3(32, 8), 0, stream>>>(Wv, wkv_t + 256ull * 2048, 2048, 256);
  cvt_wt_kernel<<<dim3(64, 64), dim3(32, 8), 0, stream>>>(Wo, wo_t, 2048, 2048);

  gemm_bt_kernel<0><<<dim3(16, 32), 256, 0, stream>>>(xbf, wq_t, qproj, 4096, 2048, 2048);
  gemm_bt_kernel<0><<<dim3(4, 32),  256, 0, stream>>>(xbf, wkv_t, kvproj, 4096, 512, 2048);

  rope_kernel<<<16384, 256, 0, stream>>>(qproj, qbuf, 3, 2048, 0);   // Q: 8 heads
  rope_kernel<<<2048, 256, 0, stream>>>(kvproj, kb, 0, 512, 0);      // K: 1 kv head
  vt_kernel<<<4096, 256, 0, stream>>>(kvproj, vtb);

  flash_kernel<<<dim3(32, 16), 256, 0, stream>>>(qbuf, kb, vtb, attn_o);

  gemm_bt_kernel<1><<<dim3(16, 32), 256, 0, stream>>>(attn_o, wo_t, out, 4096, 2048, 2048);
}

// Round 3
// 393.439 us; speedup vs baseline: 1.5592x; 1.5592x over previous
//
#include <hip/hip_runtime.h>

typedef unsigned short u16;
typedef __attribute__((ext_vector_type(8))) short short8x;
typedef __attribute__((ext_vector_type(4))) float f32x4;

#define B_ 2
#define L_ 2048
#define HID_ 2048
#define H_ 8
#define HD_ 256

__device__ __forceinline__ u16 f2bf(float f) {
  union { float f; unsigned u; } v; v.f = f;
  unsigned r = v.u + 0x7FFFu + ((v.u >> 16) & 1u);
  return (u16)(r >> 16);
}
__device__ __forceinline__ float bf2f(u16 u) {
  union { unsigned u; float f; } v; v.u = ((unsigned)u) << 16;
  return v.f;
}

// x fp32 -> bf16, same layout. grid = nelem/4/256
__global__ __launch_bounds__(256) void cvt_x_kernel(const float4* __restrict__ in,
                                                    u16* __restrict__ out) {
  int idx = blockIdx.x * 256 + threadIdx.x;
  float4 v = in[idx];
  u16* o = out + (size_t)idx * 4;
  o[0] = f2bf(v.x); o[1] = f2bf(v.y); o[2] = f2bf(v.z); o[3] = f2bf(v.w);
}

// W fp32 [K][N] -> Wt bf16 [N][K]. grid (N/32, K/32), block (32,8)
__global__ __launch_bounds__(256) void cvt_wt_kernel(const float* __restrict__ W,
                                                     u16* __restrict__ Wt, int K, int N) {
  __shared__ float tile[32][33];
  int n0 = blockIdx.x * 32, k0 = blockIdx.y * 32;
  int tx = threadIdx.x, ty = threadIdx.y;
#pragma unroll
  for (int i = 0; i < 32; i += 8)
    tile[ty + i][tx] = W[(size_t)(k0 + ty + i) * N + n0 + tx];
  __syncthreads();
#pragma unroll
  for (int i = 0; i < 32; i += 8)
    Wt[(size_t)(n0 + ty + i) * K + k0 + tx] = f2bf(tile[tx][ty + i]);
}

// RoPE + head-permute + optional scale (folds 1/sqrt(HD) into Q).
// in: bf16 [B*L][in_stride] (+off); out: bf16 [(b*nh+h)*L + l][256]
__global__ __launch_bounds__(256) void rope_kernel(const u16* __restrict__ in,
                                                   u16* __restrict__ out, int nh_shift,
                                                   int in_stride, int in_off, float scale) {
  int idx = blockIdx.x * 256 + threadIdx.x;
  int nh = 1 << nh_shift;
  int d = idx & 127;
  int t = idx >> 7;
  int h = t & (nh - 1);
  int row = t >> nh_shift;  // b*L + l
  int l = row & (L_ - 1);
  int b = row >> 11;
  size_t ibase = (size_t)row * in_stride + in_off + h * 256 + d;
  float x1 = bf2f(in[ibase]);
  float x2 = bf2f(in[ibase + 128]);
  float f = exp2f(-(float)d * (13.287712379549449f / 128.0f));
  float ang = (float)l * f;
  float s, c;
  sincosf(ang, &s, &c);
  size_t obase = ((size_t)(b * nh + h) * L_ + l) * 256 + d;
  out[obase] = f2bf((x1 * c - x2 * s) * scale);
  out[obase + 128] = f2bf((x2 * c + x1 * s) * scale);
}

// kvproj bf16 [B*L][512] (V at col off 256) -> vt bf16 [(b*256+d)][L]
__global__ __launch_bounds__(256) void vt_kernel(const u16* __restrict__ kvproj,
                                                 u16* __restrict__ vt) {
  int idx = blockIdx.x * 256 + threadIdx.x;  // = (b*256+d)*2048 + l
  int l = idx & 2047;
  int d = (idx >> 11) & 255;
  int b = idx >> 19;
  vt[idx] = kvproj[((size_t)b * 2048 + l) * 512 + 256 + d];
}

// C[M][N] = A[M][K] @ Bt[N][K]^T, bf16 in, fp32 acc, bf16 or fp32 out.
// 128x128 tile, BK=32, 4 waves in 2x2, each wave 64x64 (4x4 fragments).
template <int F32OUT>
__global__ __launch_bounds__(256) void gemm_bt_kernel(const u16* __restrict__ A,
                                                      const u16* __restrict__ Bt,
                                                      void* __restrict__ Cv,
                                                      int M, int N, int K) {
  __shared__ u16 As[128 * 32];
  __shared__ u16 Bs[128 * 32];
  const int tid = threadIdx.x;
  const int lane = tid & 63;
  const int w = tid >> 6;
  const int wr = w >> 1, wc = w & 1;
  const int m0 = blockIdx.y * 128, n0 = blockIdx.x * 128;
  const int l15 = lane & 15, l4 = lane >> 4;
  f32x4 acc[4][4] = {};
  for (int kt = 0; kt < K; kt += 32) {
#pragma unroll
    for (int i = 0; i < 2; ++i) {
      int c = tid + i * 256;
      int row = c >> 2, cin = c & 3;
      *(float4*)(&As[row * 32 + cin * 8]) =
          *(const float4*)(A + (size_t)(m0 + row) * K + kt + cin * 8);
      *(float4*)(&Bs[row * 32 + cin * 8]) =
          *(const float4*)(Bt + (size_t)(n0 + row) * K + kt + cin * 8);
    }
    __syncthreads();
    short8x a[4], b[4];
#pragma unroll
    for (int m = 0; m < 4; ++m)
      a[m] = *(const short8x*)(&As[(wr * 64 + m * 16 + l15) * 32 + l4 * 8]);
#pragma unroll
    for (int n = 0; n < 4; ++n)
      b[n] = *(const short8x*)(&Bs[(wc * 64 + n * 16 + l15) * 32 + l4 * 8]);
#pragma unroll
    for (int m = 0; m < 4; ++m)
#pragma unroll
      for (int n = 0; n < 4; ++n)
        acc[m][n] = __builtin_amdgcn_mfma_f32_16x16x32_bf16(a[m], b[n], acc[m][n], 0, 0, 0);
    __syncthreads();
  }
#pragma unroll
  for (int m = 0; m < 4; ++m) {
#pragma unroll
    for (int n = 0; n < 4; ++n) {
      int gcol = n0 + wc * 64 + n * 16 + l15;
#pragma unroll
      for (int r = 0; r < 4; ++r) {
        int grow = m0 + wr * 64 + m * 16 + l4 * 4 + r;
        if (F32OUT)
          ((float*)Cv)[(size_t)grow * N + gcol] = acc[m][n][r];
        else
          ((u16*)Cv)[(size_t)grow * N + gcol] = f2bf(acc[m][n][r]);
      }
    }
  }
}

// Flash attention v3. qb: [B*H][L][256] (pre-scaled by HD^-0.5), kb: [B][L][256],
// vt: [B][256][L], attn_o: [B*L][H*256].
// 256 threads (4 waves x 16 q-rows, QBLK=64), KVBLK=64.
// grid = (32, B*H); qt = 31 - blockIdx.x (heavy blocks first).
// Direct global->LDS staging (XOR-swizzled); NO launch_bounds min-waves:
// VGPR in (128,256] still gives 8 waves/CU (2 blocks) per m69, without spill.
__global__ __launch_bounds__(256) void flash_kernel(const u16* __restrict__ qb,
                                                    const u16* __restrict__ kb,
                                                    const u16* __restrict__ vt,
                                                    u16* __restrict__ attn_o) {
  __shared__ u16 Ks[64 * 256];    // [row k][d], byte ^= (row&7)<<4
  __shared__ u16 Vts[256 * 64];   // [row d][k], byte ^= (d&7)<<4
  __shared__ u16 Ps[4 * 16 * 72]; // per-wave [16][64] padded to 72
  const int qt = 31 - (int)blockIdx.x;
  const int bh = blockIdx.y;
  const int b = bh >> 3;
  const int h = bh & 7;
  const int tid = threadIdx.x, lane = tid & 63, w = tid >> 6;
  const int l15 = lane & 15, l4 = lane >> 4;
  const int q0 = qt * 64;

  // Q fragments: wave w owns rows q0 + w*16 .. +15
  const u16* qrow = qb + ((size_t)bh * L_ + q0 + w * 16 + l15) * 256;
  short8x qf[8];
#pragma unroll
  for (int kc = 0; kc < 8; ++kc)
    qf[kc] = *(const short8x*)(qrow + kc * 32 + l4 * 8);

  f32x4 o[16] = {};
  float mrow[4] = {-3e38f, -3e38f, -3e38f, -3e38f};
  float srow[4] = {0.f, 0.f, 0.f, 0.f};

  const u16* kbase = kb + (size_t)b * (L_ * 256);
  const u16* vbase = vt + (size_t)b * (256 * L_);
  const int krow = tid >> 5, kcol = tid & 31;  // K: +8 rows per pass
  const int vrow = tid >> 3, vcol = tid & 7;   // V^T: +32 rows per pass

  for (int t = 0; t <= qt; ++t) {
    __syncthreads();  // previous tile's LDS reads done
#pragma unroll
    for (int i = 0; i < 8; ++i) {
      int rk = krow + i * 8;
      *(float4*)((char*)Ks + (((rk * 256 + kcol * 8) * 2) ^ ((rk & 7) << 4))) =
          *(const float4*)(kbase + ((size_t)(t * 64 + rk)) * 256 + kcol * 8);
      int rd = vrow + i * 32;
      *(float4*)((char*)Vts + (((rd * 64 + vcol * 8) * 2) ^ ((rd & 7) << 4))) =
          *(const float4*)(vbase + (size_t)rd * L_ + t * 64 + vcol * 8);
    }
    __syncthreads();
    // S = Q K^T : 16 rows x 64 cols, contraction over d=256
    f32x4 sacc[4] = {};
#pragma unroll
    for (int kc = 0; kc < 8; ++kc)
#pragma unroll
      for (int n = 0; n < 4; ++n) {
        int row = n * 16 + l15;
        short8x kf = *(const short8x*)((char*)Ks +
            (((row * 256 + kc * 32 + l4 * 8) * 2) ^ ((row & 7) << 4)));
        sacc[n] = __builtin_amdgcn_mfma_f32_16x16x32_bf16(qf[kc], kf, sacc[n], 0, 0, 0);
      }
    float p[4][4];
    const bool dm = (t == qt);
#pragma unroll
    for (int n = 0; n < 4; ++n) {
      int jg = t * 64 + n * 16 + l15;
#pragma unroll
      for (int r = 0; r < 4; ++r) {
        float v = sacc[n][r];  // scale pre-folded into Q
        if (dm && (jg > q0 + w * 16 + l4 * 4 + r)) v = -1e30f;
        p[n][r] = v;
      }
    }
    float alpha[4];
#pragma unroll
    for (int r = 0; r < 4; ++r) {
      float rm = fmaxf(fmaxf(p[0][r], p[1][r]), fmaxf(p[2][r], p[3][r]));
#pragma unroll
      for (int off = 1; off < 16; off <<= 1)
        rm = fmaxf(rm, __shfl_xor(rm, off));
      float mn = fmaxf(mrow[r], rm);
      alpha[r] = __expf(mrow[r] - mn);
      mrow[r] = mn;
      float rs = 0.f;
#pragma unroll
      for (int n = 0; n < 4; ++n) {
        p[n][r] = __expf(p[n][r] - mn);
        rs += p[n][r];
      }
#pragma unroll
      for (int off = 1; off < 16; off <<= 1)
        rs += __shfl_xor(rs, off);
      srow[r] = srow[r] * alpha[r] + rs;
    }
#pragma unroll
    for (int ff = 0; ff < 16; ++ff) {
      o[ff][0] *= alpha[0]; o[ff][1] *= alpha[1];
      o[ff][2] *= alpha[2]; o[ff][3] *= alpha[3];
    }
    // P (C-layout) -> LDS -> A-layout fragments
#pragma unroll
    for (int n = 0; n < 4; ++n)
#pragma unroll
      for (int r = 0; r < 4; ++r)
        Ps[w * 1152 + (l4 * 4 + r) * 72 + n * 16 + l15] = f2bf(p[n][r]);
    asm volatile("s_waitcnt lgkmcnt(0)" ::: "memory");
    short8x paf[2];
#pragma unroll
    for (int kc2 = 0; kc2 < 2; ++kc2)
      paf[kc2] = *(const short8x*)(&Ps[w * 1152 + l15 * 72 + kc2 * 32 + l4 * 8]);
    // O += P V : contraction over j=64
#pragma unroll
    for (int kc2 = 0; kc2 < 2; ++kc2)
#pragma unroll
      for (int ff = 0; ff < 16; ++ff) {
        int rd = ff * 16 + l15;
        short8x vf = *(const short8x*)((char*)Vts +
            (((rd * 64 + kc2 * 32 + l4 * 8) * 2) ^ ((rd & 7) << 4)));
        o[ff] = __builtin_amdgcn_mfma_f32_16x16x32_bf16(paf[kc2], vf, o[ff], 0, 0, 0);
      }
  }
#pragma unroll
  for (int r = 0; r < 4; ++r) {
    float inv = 1.0f / srow[r];
    int grow = q0 + w * 16 + l4 * 4 + r;
    size_t base = ((size_t)b * L_ + grow) * (size_t)(H_ * HD_) + h * 256;
#pragma unroll
    for (int ff = 0; ff < 16; ++ff)
      attn_o[base + ff * 16 + l15] = f2bf(o[ff][r] * inv);
  }
}

extern "C" void kernel_launch(void* const* d_in, const int* in_sizes, int n_in,
                              void* d_out, int out_size, void* d_ws, size_t ws_size,
                              hipStream_t stream) {
  const float* x  = (const float*)d_in[0];
  const float* Wq = (const float*)d_in[1];
  const float* Wk = (const float*)d_in[2];
  const float* Wv = (const float*)d_in[3];
  const float* Wo = (const float*)d_in[4];
  // d_in[5] = additive causal mask: semantics reproduced analytically, not read.
  float* out = (float*)d_out;
  char* ws = (char*)d_ws;
  size_t off = 0;
  auto alloc = [&](size_t bytes) {
    void* p = ws + off;
    off = (off + bytes + 255) & ~(size_t)255;
    return p;
  };
  u16* wq_t   = (u16*)alloc(2048ull * 2048 * 2);  // [2048][2048] = Wq^T
  u16* wkv_t  = (u16*)alloc(512ull * 2048 * 2);   // rows 0..255 = Wk^T, 256..511 = Wv^T
  u16* wo_t   = (u16*)alloc(2048ull * 2048 * 2);
  u16* xbf    = (u16*)alloc(4096ull * 2048 * 2);  // reused as roped Q
  u16* qproj  = (u16*)alloc(4096ull * 2048 * 2);  // reused as attn output
  u16* kvproj = (u16*)alloc(4096ull * 512 * 2);   // [B*L][512]: K | V
  u16* kb     = (u16*)alloc(4096ull * 256 * 2);
  u16* vtb    = (u16*)alloc(4096ull * 256 * 2);
  u16* qbuf   = xbf;    // alias: x_bf dead after KV projection
  u16* attn_o = qproj;  // alias: qproj dead after rope_q

  cvt_x_kernel<<<8192, 256, 0, stream>>>((const float4*)x, xbf);
  cvt_wt_kernel<<<dim3(64, 64), dim3(32, 8), 0, stream>>>(Wq, wq_t, 2048, 2048);
  cvt_wt_kernel<<<dim3(8, 64),  dim3(32, 8), 0, stream>>>(Wk, wkv_t, 2048, 256);
  cvt_wt_kernel<<<dim3(8, 64),  dim3(32, 8), 0, stream>>>(Wv, wkv_t + 256ull * 2048, 2048, 256);
  cvt_wt_kernel<<<dim3(64, 64), dim3(32, 8), 0, stream>>>(Wo, wo_t, 2048, 2048);

  gemm_bt_kernel<0><<<dim3(16, 32), 256, 0, stream>>>(xbf, wq_t, qproj, 4096, 2048, 2048);
  gemm_bt_kernel<0><<<dim3(4, 32),  256, 0, stream>>>(xbf, wkv_t, kvproj, 4096, 512, 2048);

  rope_kernel<<<16384, 256, 0, stream>>>(qproj, qbuf, 3, 2048, 0, 0.0625f);  // Q (scaled)
  rope_kernel<<<2048, 256, 0, stream>>>(kvproj, kb, 0, 512, 0, 1.0f);        // K
  vt_kernel<<<4096, 256, 0, stream>>>(kvproj, vtb);

  flash_kernel<<<dim3(32, 16), 256, 0, stream>>>(qbuf, kb, vtb, attn_o);

  gemm_bt_kernel<1><<<dim3(16, 32), 256, 0, stream>>>(attn_o, wo_t, out, 4096, 2048, 2048);
}

// Round 5
// 321.887 us; speedup vs baseline: 1.9058x; 1.2223x over previous
//
#include <hip/hip_runtime.h>

typedef unsigned short u16;
typedef __attribute__((ext_vector_type(8))) short short8x;
typedef __attribute__((ext_vector_type(4))) float f32x4;

#define B_ 2
#define L_ 2048
#define HID_ 2048
#define H_ 8
#define HD_ 256

__device__ __forceinline__ u16 f2bf(float f) {
  union { float f; unsigned u; } v; v.f = f;
  unsigned r = v.u + 0x7FFFu + ((v.u >> 16) & 1u);
  return (u16)(r >> 16);
}
__device__ __forceinline__ float bf2f(u16 u) {
  union { unsigned u; float f; } v; v.u = ((unsigned)u) << 16;
  return v.f;
}

// async global->LDS, 16B per lane. lds ptr must be the wave-uniform base;
// HW adds lane*16. size arg is a literal (guide: global_load_lds width=16).
__device__ __forceinline__ void gload_lds16(const void* g, void* l) {
  __builtin_amdgcn_global_load_lds((const __attribute__((address_space(1))) unsigned*)g,
                                   (__attribute__((address_space(3))) unsigned*)l, 16, 0, 0);
}

// x fp32 -> bf16, same layout. grid = nelem/4/256
__global__ __launch_bounds__(256) void cvt_x_kernel(const float4* __restrict__ in,
                                                    u16* __restrict__ out) {
  int idx = blockIdx.x * 256 + threadIdx.x;
  float4 v = in[idx];
  u16* o = out + (size_t)idx * 4;
  o[0] = f2bf(v.x); o[1] = f2bf(v.y); o[2] = f2bf(v.z); o[3] = f2bf(v.w);
}

// W fp32 [K][N] -> Wt bf16 [N][K]. grid (N/32, K/32), block (32,8)
__global__ __launch_bounds__(256) void cvt_wt_kernel(const float* __restrict__ W,
                                                     u16* __restrict__ Wt, int K, int N) {
  __shared__ float tile[32][33];
  int n0 = blockIdx.x * 32, k0 = blockIdx.y * 32;
  int tx = threadIdx.x, ty = threadIdx.y;
#pragma unroll
  for (int i = 0; i < 32; i += 8)
    tile[ty + i][tx] = W[(size_t)(k0 + ty + i) * N + n0 + tx];
  __syncthreads();
#pragma unroll
  for (int i = 0; i < 32; i += 8)
    Wt[(size_t)(n0 + ty + i) * K + k0 + tx] = f2bf(tile[tx][ty + i]);
}

// RoPE + head-permute + optional scale (folds 1/sqrt(HD) into Q).
__global__ __launch_bounds__(256) void rope_kernel(const u16* __restrict__ in,
                                                   u16* __restrict__ out, int nh_shift,
                                                   int in_stride, int in_off, float scale) {
  int idx = blockIdx.x * 256 + threadIdx.x;
  int nh = 1 << nh_shift;
  int d = idx & 127;
  int t = idx >> 7;
  int h = t & (nh - 1);
  int row = t >> nh_shift;  // b*L + l
  int l = row & (L_ - 1);
  int b = row >> 11;
  size_t ibase = (size_t)row * in_stride + in_off + h * 256 + d;
  float x1 = bf2f(in[ibase]);
  float x2 = bf2f(in[ibase + 128]);
  float f = exp2f(-(float)d * (13.287712379549449f / 128.0f));
  float ang = (float)l * f;
  float s, c;
  sincosf(ang, &s, &c);
  size_t obase = ((size_t)(b * nh + h) * L_ + l) * 256 + d;
  out[obase] = f2bf((x1 * c - x2 * s) * scale);
  out[obase + 128] = f2bf((x2 * c + x1 * s) * scale);
}

// kvproj bf16 [B*L][512] (V at col off 256) -> vt bf16 [(b*256+d)][L]
__global__ __launch_bounds__(256) void vt_kernel(const u16* __restrict__ kvproj,
                                                 u16* __restrict__ vt) {
  int idx = blockIdx.x * 256 + threadIdx.x;  // = (b*256+d)*2048 + l
  int l = idx & 2047;
  int d = (idx >> 11) & 255;
  int b = idx >> 19;
  vt[idx] = kvproj[((size_t)b * 2048 + l) * 512 + 256 + d];
}

// C[M][N] = A[M][K] @ Bt[N][K]^T, bf16 in, fp32 acc, bf16 or fp32 out.
// 128x128 tile, BK=32, 4 waves 2x2; m97-style global_load_lds staging.
template <int F32OUT>
__global__ __launch_bounds__(256) void gemm_bt_kernel(const u16* __restrict__ A,
                                                      const u16* __restrict__ Bt,
                                                      void* __restrict__ Cv,
                                                      int M, int N, int K) {
  __shared__ __attribute__((aligned(16))) u16 As[128 * 32];
  __shared__ __attribute__((aligned(16))) u16 Bs[128 * 32];
  const int tid = threadIdx.x;
  const int lane = tid & 63;
  const int w = tid >> 6;
  const int wr = w >> 1, wc = w & 1;
  const int m0 = blockIdx.y * 128, n0 = blockIdx.x * 128;
  const int l15 = lane & 15, l4 = lane >> 4;
  f32x4 acc[4][4] = {};
  for (int kt = 0; kt < K; kt += 32) {
#pragma unroll
    for (int i = 0; i < 2; ++i) {
      int c = tid + i * 256;
      int row = c >> 2, cin = c & 3;  // linear LDS: byte off = c*16
      gload_lds16(A + (size_t)(m0 + row) * K + kt + cin * 8,
                  (char*)As + (i * 256 + w * 64) * 16);
      gload_lds16(Bt + (size_t)(n0 + row) * K + kt + cin * 8,
                  (char*)Bs + (i * 256 + w * 64) * 16);
    }
    __syncthreads();
    short8x a[4], b[4];
#pragma unroll
    for (int m = 0; m < 4; ++m)
      a[m] = *(const short8x*)(&As[(wr * 64 + m * 16 + l15) * 32 + l4 * 8]);
#pragma unroll
    for (int n = 0; n < 4; ++n)
      b[n] = *(const short8x*)(&Bs[(wc * 64 + n * 16 + l15) * 32 + l4 * 8]);
#pragma unroll
    for (int m = 0; m < 4; ++m)
#pragma unroll
      for (int n = 0; n < 4; ++n)
        acc[m][n] = __builtin_amdgcn_mfma_f32_16x16x32_bf16(a[m], b[n], acc[m][n], 0, 0, 0);
    __syncthreads();
  }
#pragma unroll
  for (int m = 0; m < 4; ++m) {
#pragma unroll
    for (int n = 0; n < 4; ++n) {
      int gcol = n0 + wc * 64 + n * 16 + l15;
#pragma unroll
      for (int r = 0; r < 4; ++r) {
        int grow = m0 + wr * 64 + m * 16 + l4 * 4 + r;
        if (F32OUT)
          ((float*)Cv)[(size_t)grow * N + gcol] = acc[m][n][r];
        else
          ((u16*)Cv)[(size_t)grow * N + gcol] = f2bf(acc[m][n][r]);
      }
    }
  }
}

// Flash attention v5 — GQA-shared staging, dual q-tile pairing, LDS dbuf.
// qb: [B*H][L][256] (Q pre-scaled), kb: [B][L][256], vt: [B][256][L],
// attn_o: [B*L][H*256].
// grid = (64 pairs, 2 head-groups, B). block = 512 thr = 8 waves.
// wave w: head = hg*4 + (w&3); q-tile (16 rows) = (w<4) ? 127-ip : ip.
// QBLK=16 < KVBLK=64: q-tile qt lies entirely inside k-tile tq = qt>>2,
// so wave is active for t <= tq and the diagonal mask applies at t == tq.
// Each step stages K/V once (global_load_lds, double-buffered, source
// pre-swizzled so linear DMA + XOR'd ds_read agree) for all 8 waves.
__global__ __launch_bounds__(512) void flash_kernel(const u16* __restrict__ qb,
                                                    const u16* __restrict__ kb,
                                                    const u16* __restrict__ vt,
                                                    u16* __restrict__ attn_o) {
  __shared__ __attribute__((aligned(16))) u16 Kbuf[2][64 * 256];  // [k][d], read ^(k&7)<<4
  __shared__ __attribute__((aligned(16))) u16 Vbuf[2][256 * 64];  // [d][k], read ^(d&7)<<4
  __shared__ __attribute__((aligned(16))) u16 Ps[8 * 16 * 72];    // per-wave [16][64] pad 72
  const int ip = blockIdx.x;          // 0..63
  const int hg = blockIdx.y;          // 0..1
  const int b = blockIdx.z;
  const int tid = threadIdx.x, lane = tid & 63, w = tid >> 6;
  const int l15 = lane & 15, l4 = lane >> 4;
  const int head = hg * 4 + (w & 3);
  const int qt = (w < 4) ? (127 - ip) : ip;
  const int q0 = qt * 16;
  const int tq = qt >> 2;             // diagonal k-tile for this wave
  const int nt = ((127 - ip) >> 2) + 1;  // block step count (heavy bound)

  const u16* qrow = qb + ((size_t)(b * 8 + head) * L_ + q0 + l15) * 256;
  short8x qf[8];
#pragma unroll
  for (int kc = 0; kc < 8; ++kc)
    qf[kc] = *(const short8x*)(qrow + kc * 32 + l4 * 8);

  f32x4 o[16] = {};
  float mrow[4] = {-3e38f, -3e38f, -3e38f, -3e38f};
  float srow[4] = {0.f, 0.f, 0.f, 0.f};

  const u16* kbase = kb + (size_t)b * (L_ * 256);
  const u16* vbase = vt + (size_t)b * (256 * L_);

  // stage: 2048 16B-chunks each for K and V; 4 per thread.
  // linear LDS chunk c holds global column-chunk (c%W) ^ (row&7)  (involution
  // with the read-side XOR). K: W=32 chunks/row; V: W=8 chunks/row.
#define STAGE(t, s)                                                              \
  {                                                                              \
    _Pragma("unroll") for (int i2 = 0; i2 < 4; ++i2) {                           \
      int c = i2 * 512 + tid;                                                    \
      int rk = c >> 5, cck = c & 31, jk = cck ^ (rk & 7);                        \
      gload_lds16(kbase + (size_t)((t) * 64 + rk) * 256 + jk * 8,                \
                  (char*)&Kbuf[s][0] + (i2 * 512 + w * 64) * 16);                \
      int rd = c >> 3, ccv = c & 7, jv = ccv ^ (rd & 7);                         \
      gload_lds16(vbase + (size_t)rd * L_ + (t) * 64 + jv * 8,                   \
                  (char*)&Vbuf[s][0] + (i2 * 512 + w * 64) * 16);                \
    }                                                                            \
  }

  STAGE(0, 0);
  asm volatile("s_waitcnt vmcnt(0)" ::: "memory");
  __syncthreads();

  for (int t = 0; t < nt; ++t) {
    if (t + 1 < nt) STAGE(t + 1, (t + 1) & 1);
    if (t <= tq) {
      const char* Kb = (const char*)&Kbuf[t & 1][0];
      const char* Vb = (const char*)&Vbuf[t & 1][0];
      // S = Q K^T : 16 q-rows x 64 kv
      f32x4 sacc[4] = {};
#pragma unroll
      for (int kc = 0; kc < 8; ++kc)
#pragma unroll
        for (int n = 0; n < 4; ++n) {
          int row = n * 16 + l15;
          short8x kf = *(const short8x*)(Kb +
              ((row * 512 + kc * 64 + l4 * 16) ^ ((row & 7) << 4)));
          sacc[n] = __builtin_amdgcn_mfma_f32_16x16x32_bf16(qf[kc], kf, sacc[n], 0, 0, 0);
        }
      float p[4][4];
      const bool dm = (t == tq);
#pragma unroll
      for (int n = 0; n < 4; ++n) {
        int jg = t * 64 + n * 16 + l15;
#pragma unroll
        for (int r = 0; r < 4; ++r) {
          float v = sacc[n][r];
          if (dm && (jg > q0 + l4 * 4 + r)) v = -1e30f;
          p[n][r] = v;
        }
      }
      float alpha[4];
#pragma unroll
      for (int r = 0; r < 4; ++r) {
        float rm = fmaxf(fmaxf(p[0][r], p[1][r]), fmaxf(p[2][r], p[3][r]));
#pragma unroll
        for (int off = 1; off < 16; off <<= 1)
          rm = fmaxf(rm, __shfl_xor(rm, off));
        float mn = fmaxf(mrow[r], rm);
        alpha[r] = __expf(mrow[r] - mn);
        mrow[r] = mn;
        float rs = 0.f;
#pragma unroll
        for (int n = 0; n < 4; ++n) {
          p[n][r] = __expf(p[n][r] - mn);
          rs += p[n][r];
        }
#pragma unroll
        for (int off = 1; off < 16; off <<= 1)
          rs += __shfl_xor(rs, off);
        srow[r] = srow[r] * alpha[r] + rs;
      }
#pragma unroll
      for (int ff = 0; ff < 16; ++ff) {
        o[ff][0] *= alpha[0]; o[ff][1] *= alpha[1];
        o[ff][2] *= alpha[2]; o[ff][3] *= alpha[3];
      }
      // P (C-layout) -> LDS -> A-layout fragments (per-wave private region)
#pragma unroll
      for (int n = 0; n < 4; ++n)
#pragma unroll
        for (int r = 0; r < 4; ++r)
          Ps[w * 1152 + (l4 * 4 + r) * 72 + n * 16 + l15] = f2bf(p[n][r]);
      asm volatile("s_waitcnt lgkmcnt(0)" ::: "memory");
      short8x paf[2];
#pragma unroll
      for (int kc2 = 0; kc2 < 2; ++kc2)
        paf[kc2] = *(const short8x*)(&Ps[w * 1152 + l15 * 72 + kc2 * 32 + l4 * 8]);
      // O += P V : contraction over kv=64
#pragma unroll
      for (int kc2 = 0; kc2 < 2; ++kc2)
#pragma unroll
        for (int ff = 0; ff < 16; ++ff) {
          int rd = ff * 16 + l15;
          short8x vf = *(const short8x*)(Vb +
              ((rd * 128 + kc2 * 64 + l4 * 16) ^ ((rd & 7) << 4)));
          o[ff] = __builtin_amdgcn_mfma_f32_16x16x32_bf16(paf[kc2], vf, o[ff], 0, 0, 0);
        }
    }
    asm volatile("s_waitcnt vmcnt(0)" ::: "memory");
    __syncthreads();
  }
#pragma unroll
  for (int r = 0; r < 4; ++r) {
    float inv = 1.0f / srow[r];
    int grow = q0 + l4 * 4 + r;
    size_t base = ((size_t)b * L_ + grow) * (size_t)(H_ * HD_) + head * 256;
#pragma unroll
    for (int ff = 0; ff < 16; ++ff)
      attn_o[base + ff * 16 + l15] = f2bf(o[ff][r] * inv);
  }
#undef STAGE
}

extern "C" void kernel_launch(void* const* d_in, const int* in_sizes, int n_in,
                              void* d_out, int out_size, void* d_ws, size_t ws_size,
                              hipStream_t stream) {
  const float* x  = (const float*)d_in[0];
  const float* Wq = (const float*)d_in[1];
  const float* Wk = (const float*)d_in[2];
  const float* Wv = (const float*)d_in[3];
  const float* Wo = (const float*)d_in[4];
  // d_in[5] = additive causal mask: semantics reproduced analytically, not read.
  float* out = (float*)d_out;
  char* ws = (char*)d_ws;
  size_t off = 0;
  auto alloc = [&](size_t bytes) {
    void* p = ws + off;
    off = (off + bytes + 255) & ~(size_t)255;
    return p;
  };
  u16* wq_t   = (u16*)alloc(2048ull * 2048 * 2);  // [2048][2048] = Wq^T
  u16* wkv_t  = (u16*)alloc(512ull * 2048 * 2);   // rows 0..255 = Wk^T, 256..511 = Wv^T
  u16* wo_t   = (u16*)alloc(2048ull * 2048 * 2);
  u16* xbf    = (u16*)alloc(4096ull * 2048 * 2);  // reused as roped Q
  u16* qproj  = (u16*)alloc(4096ull * 2048 * 2);  // reused as attn output
  u16* kvproj = (u16*)alloc(4096ull * 512 * 2);   // [B*L][512]: K | V
  u16* kb     = (u16*)alloc(4096ull * 256 * 2);
  u16* vtb    = (u16*)alloc(4096ull * 256 * 2);
  u16* qbuf   = xbf;    // alias: x_bf dead after KV projection
  u16* attn_o = qproj;  // alias: qproj dead after rope_q

  cvt_x_kernel<<<8192, 256, 0, stream>>>((const float4*)x, xbf);
  cvt_wt_kernel<<<dim3(64, 64), dim3(32, 8), 0, stream>>>(Wq, wq_t, 2048, 2048);
  cvt_wt_kernel<<<dim3(8, 64),  dim3(32, 8), 0, stream>>>(Wk, wkv_t, 2048, 256);
  cvt_wt_kernel<<<dim3(8, 64),  dim3(32, 8), 0, stream>>>(Wv, wkv_t + 256ull * 2048, 2048, 256);
  cvt_wt_kernel<<<dim3(64, 64), dim3(32, 8), 0, stream>>>(Wo, wo_t, 2048, 2048);

  gemm_bt_kernel<0><<<dim3(16, 32), 256, 0, stream>>>(xbf, wq_t, qproj, 4096, 2048, 2048);
  gemm_bt_kernel<0><<<dim3(4, 32),  256, 0, stream>>>(xbf, wkv_t, kvproj, 4096, 512, 2048);

  rope_kernel<<<16384, 256, 0, stream>>>(qproj, qbuf, 3, 2048, 0, 0.0625f);  // Q (scaled)
  rope_kernel<<<2048, 256, 0, stream>>>(kvproj, kb, 0, 512, 0, 1.0f);        // K
  vt_kernel<<<4096, 256, 0, stream>>>(kvproj, vtb);

  flash_kernel<<<dim3(64, 2, 2), 512, 0, stream>>>(qbuf, kb, vtb, attn_o);

  gemm_bt_kernel<1><<<dim3(16, 32), 256, 0, stream>>>(attn_o, wo_t, out, 4096, 2048, 2048);
}

// Round 6
// 305.486 us; speedup vs baseline: 2.0081x; 1.0537x over previous
//
#include <hip/hip_runtime.h>

typedef unsigned short u16;
typedef __attribute__((ext_vector_type(8))) short short8x;
typedef __attribute__((ext_vector_type(4))) float f32x4;

#define B_ 2
#define L_ 2048
#define HID_ 2048
#define H_ 8
#define HD_ 256

__device__ __forceinline__ u16 f2bf(float f) {
  union { float f; unsigned u; } v; v.f = f;
  unsigned r = v.u + 0x7FFFu + ((v.u >> 16) & 1u);
  return (u16)(r >> 16);
}
__device__ __forceinline__ float bf2f(u16 u) {
  union { unsigned u; float f; } v; v.u = ((unsigned)u) << 16;
  return v.f;
}

// async global->LDS, 16B per lane. lds ptr must be the wave-uniform base;
// HW adds lane*16. size arg is a literal (guide: global_load_lds width=16).
__device__ __forceinline__ void gload_lds16(const void* g, void* l) {
  __builtin_amdgcn_global_load_lds((const __attribute__((address_space(1))) unsigned*)g,
                                   (__attribute__((address_space(3))) unsigned*)l, 16, 0, 0);
}

// x fp32 -> bf16, same layout. grid = nelem/4/256
__global__ __launch_bounds__(256) void cvt_x_kernel(const float4* __restrict__ in,
                                                    u16* __restrict__ out) {
  int idx = blockIdx.x * 256 + threadIdx.x;
  float4 v = in[idx];
  u16* o = out + (size_t)idx * 4;
  o[0] = f2bf(v.x); o[1] = f2bf(v.y); o[2] = f2bf(v.z); o[3] = f2bf(v.w);
}

// W fp32 [K][N] -> Wt bf16 [N][K]. grid (N/32, K/32), block (32,8)
__global__ __launch_bounds__(256) void cvt_wt_kernel(const float* __restrict__ W,
                                                     u16* __restrict__ Wt, int K, int N) {
  __shared__ float tile[32][33];
  int n0 = blockIdx.x * 32, k0 = blockIdx.y * 32;
  int tx = threadIdx.x, ty = threadIdx.y;
#pragma unroll
  for (int i = 0; i < 32; i += 8)
    tile[ty + i][tx] = W[(size_t)(k0 + ty + i) * N + n0 + tx];
  __syncthreads();
#pragma unroll
  for (int i = 0; i < 32; i += 8)
    Wt[(size_t)(n0 + ty + i) * K + k0 + tx] = f2bf(tile[tx][ty + i]);
}

// RoPE + head-permute + optional scale (folds 1/sqrt(HD) into Q).
__global__ __launch_bounds__(256) void rope_kernel(const u16* __restrict__ in,
                                                   u16* __restrict__ out, int nh_shift,
                                                   int in_stride, int in_off, float scale) {
  int idx = blockIdx.x * 256 + threadIdx.x;
  int nh = 1 << nh_shift;
  int d = idx & 127;
  int t = idx >> 7;
  int h = t & (nh - 1);
  int row = t >> nh_shift;  // b*L + l
  int l = row & (L_ - 1);
  int b = row >> 11;
  size_t ibase = (size_t)row * in_stride + in_off + h * 256 + d;
  float x1 = bf2f(in[ibase]);
  float x2 = bf2f(in[ibase + 128]);
  float f = exp2f(-(float)d * (13.287712379549449f / 128.0f));
  float ang = (float)l * f;
  float s, c;
  sincosf(ang, &s, &c);
  size_t obase = ((size_t)(b * nh + h) * L_ + l) * 256 + d;
  out[obase] = f2bf((x1 * c - x2 * s) * scale);
  out[obase + 128] = f2bf((x2 * c + x1 * s) * scale);
}

// kvproj bf16 [B*L][512] (V at col off 256) -> vt bf16 [(b*256+d)][L]
__global__ __launch_bounds__(256) void vt_kernel(const u16* __restrict__ kvproj,
                                                 u16* __restrict__ vt) {
  int idx = blockIdx.x * 256 + threadIdx.x;  // = (b*256+d)*2048 + l
  int l = idx & 2047;
  int d = (idx >> 11) & 255;
  int b = idx >> 19;
  vt[idx] = kvproj[((size_t)b * 2048 + l) * 512 + 256 + d];
}

// C[M][N] = A[M][K] @ Bt[N][K]^T, bf16 in, fp32 acc, bf16 or fp32 out.
// 128x128 tile, BK=32, 4 waves 2x2; m97-style global_load_lds staging.
template <int F32OUT>
__global__ __launch_bounds__(256) void gemm_bt_kernel(const u16* __restrict__ A,
                                                      const u16* __restrict__ Bt,
                                                      void* __restrict__ Cv,
                                                      int M, int N, int K) {
  __shared__ __attribute__((aligned(16))) u16 As[128 * 32];
  __shared__ __attribute__((aligned(16))) u16 Bs[128 * 32];
  const int tid = threadIdx.x;
  const int lane = tid & 63;
  const int w = tid >> 6;
  const int wr = w >> 1, wc = w & 1;
  const int m0 = blockIdx.y * 128, n0 = blockIdx.x * 128;
  const int l15 = lane & 15, l4 = lane >> 4;
  f32x4 acc[4][4] = {};
  for (int kt = 0; kt < K; kt += 32) {
#pragma unroll
    for (int i = 0; i < 2; ++i) {
      int c = tid + i * 256;
      int row = c >> 2, cin = c & 3;  // linear LDS: byte off = c*16
      gload_lds16(A + (size_t)(m0 + row) * K + kt + cin * 8,
                  (char*)As + (i * 256 + w * 64) * 16);
      gload_lds16(Bt + (size_t)(n0 + row) * K + kt + cin * 8,
                  (char*)Bs + (i * 256 + w * 64) * 16);
    }
    __syncthreads();
    short8x a[4], b[4];
#pragma unroll
    for (int m = 0; m < 4; ++m)
      a[m] = *(const short8x*)(&As[(wr * 64 + m * 16 + l15) * 32 + l4 * 8]);
#pragma unroll
    for (int n = 0; n < 4; ++n)
      b[n] = *(const short8x*)(&Bs[(wc * 64 + n * 16 + l15) * 32 + l4 * 8]);
#pragma unroll
    for (int m = 0; m < 4; ++m)
#pragma unroll
      for (int n = 0; n < 4; ++n)
        acc[m][n] = __builtin_amdgcn_mfma_f32_16x16x32_bf16(a[m], b[n], acc[m][n], 0, 0, 0);
    __syncthreads();
  }
#pragma unroll
  for (int m = 0; m < 4; ++m) {
#pragma unroll
    for (int n = 0; n < 4; ++n) {
      int gcol = n0 + wc * 64 + n * 16 + l15;
#pragma unroll
      for (int r = 0; r < 4; ++r) {
        int grow = m0 + wr * 64 + m * 16 + l4 * 4 + r;
        if (F32OUT)
          ((float*)Cv)[(size_t)grow * N + gcol] = acc[m][n][r];
        else
          ((u16*)Cv)[(size_t)grow * N + gcol] = f2bf(acc[m][n][r]);
      }
    }
  }
}

// Flash attention v6 — uniform-tq blocks + swapped-QK in-lane softmax.
// qb: [B*H][L][256] (Q pre-scaled), kb: [B][L][256], vt: [B][256][L],
// attn_o: [B*L][H*256].
// grid.x = 256: j = 15 - (x>>4) (128-row Q-block, heavy first), bh = x&15.
// 8 waves; wave w owns q-rows j*128 + w*16 .. +15. All waves share the k-tile
// stream 0..2j+1 (tq differs by at most 1 across waves -> no tail starvation).
// Swapped QK: mfma(K,Q) gives C row=kv, col=q -> softmax reduction is in-lane
// + 2 shfl_xor (vs 32 shfls with the unswapped layout).
__global__ __launch_bounds__(512) void flash_kernel(const u16* __restrict__ qb,
                                                    const u16* __restrict__ kb,
                                                    const u16* __restrict__ vt,
                                                    u16* __restrict__ attn_o) {
  __shared__ __attribute__((aligned(16))) u16 Kbuf[2][64 * 256];  // [k][d], read ^(k&7)<<4
  __shared__ __attribute__((aligned(16))) u16 Vbuf[2][256 * 64];  // [d][k], read ^(d&7)<<4
  __shared__ __attribute__((aligned(16))) u16 Ps[8 * 16 * 72];    // per-wave [q16][kv64] pad 72
  const int x = blockIdx.x;
  const int j = 15 - (x >> 4);        // q-block index, heavy first
  const int bh = x & 15;
  const int b = bh >> 3;
  const int h = bh & 7;
  const int tid = threadIdx.x, lane = tid & 63, w = tid >> 6;
  const int l15 = lane & 15, l4 = lane >> 4;
  const int q0 = j * 128 + w * 16;
  const int tq = (q0 + 15) >> 6;      // diagonal k-tile: 2j (w<4) or 2j+1 (w>=4)
  const int nt = 2 * j + 2;           // shared k-step count

  const u16* qrow = qb + ((size_t)(b * 8 + h) * L_ + q0 + l15) * 256;
  short8x qf[8];
#pragma unroll
  for (int kc = 0; kc < 8; ++kc)
    qf[kc] = *(const short8x*)(qrow + kc * 32 + l4 * 8);

  f32x4 o[16] = {};
  float mrow = -3e38f, srow = 0.f;    // per-lane: q-row = l15

  const u16* kbase = kb + (size_t)b * (L_ * 256);
  const u16* vbase = vt + (size_t)b * (256 * L_);

  // stage: 2048 16B-chunks each for K and V; 4 per thread.
  // linear LDS chunk c holds global column-chunk (c%W) ^ (row&7)  (involution
  // with the read-side XOR). K: W=32 chunks/row; V: W=8 chunks/row.
#define STAGE(t, s)                                                              \
  {                                                                              \
    _Pragma("unroll") for (int i2 = 0; i2 < 4; ++i2) {                           \
      int c = i2 * 512 + tid;                                                    \
      int rk = c >> 5, cck = c & 31, jk = cck ^ (rk & 7);                        \
      gload_lds16(kbase + (size_t)((t) * 64 + rk) * 256 + jk * 8,                \
                  (char*)&Kbuf[s][0] + (i2 * 512 + w * 64) * 16);                \
      int rd = c >> 3, ccv = c & 7, jv = ccv ^ (rd & 7);                         \
      gload_lds16(vbase + (size_t)rd * L_ + (t) * 64 + jv * 8,                   \
                  (char*)&Vbuf[s][0] + (i2 * 512 + w * 64) * 16);                \
    }                                                                            \
  }

  STAGE(0, 0);
  asm volatile("s_waitcnt vmcnt(0)" ::: "memory");
  __syncthreads();

  for (int t = 0; t < nt; ++t) {
    if (t + 1 < nt) STAGE(t + 1, (t + 1) & 1);
    if (t <= tq) {
      const char* Kb = (const char*)&Kbuf[t & 1][0];
      const char* Vb = (const char*)&Vbuf[t & 1][0];
      // S^T = K Q^T : C row = kv (n*16 + l4*4+r), col = q (l15)
      f32x4 sacc[4] = {};
#pragma unroll
      for (int kc = 0; kc < 8; ++kc)
#pragma unroll
        for (int n = 0; n < 4; ++n) {
          int row = n * 16 + l15;
          short8x kf = *(const short8x*)(Kb +
              ((row * 512 + kc * 64 + l4 * 16) ^ ((row & 7) << 4)));
          sacc[n] = __builtin_amdgcn_mfma_f32_16x16x32_bf16(kf, qf[kc], sacc[n], 0, 0, 0);
        }
      // mask + in-lane softmax for q-row l15 (lane holds 16 kv values)
      float p[4][4];
      const bool dm = (t == tq);
      const int qg = q0 + l15;
      float pm = -3e38f;
#pragma unroll
      for (int n = 0; n < 4; ++n)
#pragma unroll
        for (int r = 0; r < 4; ++r) {
          int kvg = t * 64 + n * 16 + l4 * 4 + r;
          float v = sacc[n][r];
          if (dm && (kvg > qg)) v = -1e30f;
          p[n][r] = v;
          pm = fmaxf(pm, v);
        }
      pm = fmaxf(pm, __shfl_xor(pm, 16));
      pm = fmaxf(pm, __shfl_xor(pm, 32));
      float mn = fmaxf(mrow, pm);
      float alpha = __expf(mrow - mn);
      mrow = mn;
      float rs = 0.f;
#pragma unroll
      for (int n = 0; n < 4; ++n)
#pragma unroll
        for (int r = 0; r < 4; ++r) {
          p[n][r] = __expf(p[n][r] - mn);
          rs += p[n][r];
        }
      rs += __shfl_xor(rs, 16);
      rs += __shfl_xor(rs, 32);
      srow = srow * alpha + rs;
      // redistribute alpha (keyed by q=l15) to o's q-rows (l4*4+r)
      float av[4];
#pragma unroll
      for (int r = 0; r < 4; ++r)
        av[r] = __shfl(alpha, l4 * 4 + r, 16);
#pragma unroll
      for (int ff = 0; ff < 16; ++ff) {
        o[ff][0] *= av[0]; o[ff][1] *= av[1];
        o[ff][2] *= av[2]; o[ff][3] *= av[3];
      }
      // P -> LDS [q=l15][kv] (same layout as before, roles swapped)
#pragma unroll
      for (int n = 0; n < 4; ++n)
#pragma unroll
        for (int r = 0; r < 4; ++r)
          Ps[w * 1152 + l15 * 72 + n * 16 + l4 * 4 + r] = f2bf(p[n][r]);
      asm volatile("s_waitcnt lgkmcnt(0)" ::: "memory");
      short8x paf[2];
#pragma unroll
      for (int kc2 = 0; kc2 < 2; ++kc2)
        paf[kc2] = *(const short8x*)(&Ps[w * 1152 + l15 * 72 + kc2 * 32 + l4 * 8]);
      // O += P V : contraction over kv=64
#pragma unroll
      for (int kc2 = 0; kc2 < 2; ++kc2)
#pragma unroll
        for (int ff = 0; ff < 16; ++ff) {
          int rd = ff * 16 + l15;
          short8x vf = *(const short8x*)(Vb +
              ((rd * 128 + kc2 * 64 + l4 * 16) ^ ((rd & 7) << 4)));
          o[ff] = __builtin_amdgcn_mfma_f32_16x16x32_bf16(paf[kc2], vf, o[ff], 0, 0, 0);
        }
    }
    asm volatile("s_waitcnt vmcnt(0)" ::: "memory");
    __syncthreads();
  }
  // epilogue: srow lives keyed by q=l15; o rows are q=l4*4+r
  float sv[4];
#pragma unroll
  for (int r = 0; r < 4; ++r)
    sv[r] = __shfl(srow, l4 * 4 + r, 16);
#pragma unroll
  for (int r = 0; r < 4; ++r) {
    float inv = 1.0f / sv[r];
    int grow = q0 + l4 * 4 + r;
    size_t base = ((size_t)b * L_ + grow) * (size_t)(H_ * HD_) + h * 256;
#pragma unroll
    for (int ff = 0; ff < 16; ++ff)
      attn_o[base + ff * 16 + l15] = f2bf(o[ff][r] * inv);
  }
#undef STAGE
}

extern "C" void kernel_launch(void* const* d_in, const int* in_sizes, int n_in,
                              void* d_out, int out_size, void* d_ws, size_t ws_size,
                              hipStream_t stream) {
  const float* x  = (const float*)d_in[0];
  const float* Wq = (const float*)d_in[1];
  const float* Wk = (const float*)d_in[2];
  const float* Wv = (const float*)d_in[3];
  const float* Wo = (const float*)d_in[4];
  // d_in[5] = additive causal mask: semantics reproduced analytically, not read.
  float* out = (float*)d_out;
  char* ws = (char*)d_ws;
  size_t off = 0;
  auto alloc = [&](size_t bytes) {
    void* p = ws + off;
    off = (off + bytes + 255) & ~(size_t)255;
    return p;
  };
  u16* wq_t   = (u16*)alloc(2048ull * 2048 * 2);  // [2048][2048] = Wq^T
  u16* wkv_t  = (u16*)alloc(512ull * 2048 * 2);   // rows 0..255 = Wk^T, 256..511 = Wv^T
  u16* wo_t   = (u16*)alloc(2048ull * 2048 * 2);
  u16* xbf    = (u16*)alloc(4096ull * 2048 * 2);  // reused as roped Q
  u16* qproj  = (u16*)alloc(4096ull * 2048 * 2);  // reused as attn output
  u16* kvproj = (u16*)alloc(4096ull * 512 * 2);   // [B*L][512]: K | V
  u16* kb     = (u16*)alloc(4096ull * 256 * 2);
  u16* vtb    = (u16*)alloc(4096ull * 256 * 2);
  u16* qbuf   = xbf;    // alias: x_bf dead after KV projection
  u16* attn_o = qproj;  // alias: qproj dead after rope_q

  cvt_x_kernel<<<8192, 256, 0, stream>>>((const float4*)x, xbf);
  cvt_wt_kernel<<<dim3(64, 64), dim3(32, 8), 0, stream>>>(Wq, wq_t, 2048, 2048);
  cvt_wt_kernel<<<dim3(8, 64),  dim3(32, 8), 0, stream>>>(Wk, wkv_t, 2048, 256);
  cvt_wt_kernel<<<dim3(8, 64),  dim3(32, 8), 0, stream>>>(Wv, wkv_t + 256ull * 2048, 2048, 256);
  cvt_wt_kernel<<<dim3(64, 64), dim3(32, 8), 0, stream>>>(Wo, wo_t, 2048, 2048);

  gemm_bt_kernel<0><<<dim3(16, 32), 256, 0, stream>>>(xbf, wq_t, qproj, 4096, 2048, 2048);
  gemm_bt_kernel<0><<<dim3(4, 32),  256, 0, stream>>>(xbf, wkv_t, kvproj, 4096, 512, 2048);

  rope_kernel<<<16384, 256, 0, stream>>>(qproj, qbuf, 3, 2048, 0, 0.0625f);  // Q (scaled)
  rope_kernel<<<2048, 256, 0, stream>>>(kvproj, kb, 0, 512, 0, 1.0f);        // K
  vt_kernel<<<4096, 256, 0, stream>>>(kvproj, vtb);

  flash_kernel<<<256, 512, 0, stream>>>(qbuf, kb, vtb, attn_o);

  gemm_bt_kernel<1><<<dim3(16, 32), 256, 0, stream>>>(attn_o, wo_t, out, 4096, 2048, 2048);
}

// Round 7
// 262.560 us; speedup vs baseline: 2.3364x; 1.1635x over previous
//
#include <hip/hip_runtime.h>

typedef unsigned short u16;
typedef __attribute__((ext_vector_type(8))) short short8x;
typedef __attribute__((ext_vector_type(4))) float f32x4;

#define B_ 2
#define L_ 2048
#define HID_ 2048
#define H_ 8
#define HD_ 256

__device__ __forceinline__ u16 f2bf(float f) {
  union { float f; unsigned u; } v; v.f = f;
  unsigned r = v.u + 0x7FFFu + ((v.u >> 16) & 1u);
  return (u16)(r >> 16);
}
__device__ __forceinline__ float bf2f(u16 u) {
  union { unsigned u; float f; } v; v.u = ((unsigned)u) << 16;
  return v.f;
}

// async global->LDS, 16B per lane. lds ptr must be the wave-uniform base;
// HW adds lane*16.
__device__ __forceinline__ void gload_lds16(const void* g, void* l) {
  __builtin_amdgcn_global_load_lds((const __attribute__((address_space(1))) unsigned*)g,
                                   (__attribute__((address_space(3))) unsigned*)l, 16, 0, 0);
}

// x fp32 -> bf16, same layout. grid = nelem/4/256
__global__ __launch_bounds__(256) void cvt_x_kernel(const float4* __restrict__ in,
                                                    u16* __restrict__ out) {
  int idx = blockIdx.x * 256 + threadIdx.x;
  float4 v = in[idx];
  u16* o = out + (size_t)idx * 4;
  o[0] = f2bf(v.x); o[1] = f2bf(v.y); o[2] = f2bf(v.z); o[3] = f2bf(v.w);
}

// W fp32 [K][N] -> Wt bf16 [N][K] (row stride K). grid (N/32, K/32), block (32,8)
__global__ __launch_bounds__(256) void cvt_wt_kernel(const float* __restrict__ W,
                                                     u16* __restrict__ Wt, int K, int N) {
  __shared__ float tile[32][33];
  int n0 = blockIdx.x * 32, k0 = blockIdx.y * 32;
  int tx = threadIdx.x, ty = threadIdx.y;
#pragma unroll
  for (int i = 0; i < 32; i += 8)
    tile[ty + i][tx] = W[(size_t)(k0 + ty + i) * N + n0 + tx];
  __syncthreads();
#pragma unroll
  for (int i = 0; i < 32; i += 8)
    Wt[(size_t)(n0 + ty + i) * K + k0 + tx] = f2bf(tile[tx][ty + i]);
}

// RoPE + head-permute + optional scale (folds 1/sqrt(HD) into Q).
__global__ __launch_bounds__(256) void rope_kernel(const u16* __restrict__ in,
                                                   u16* __restrict__ out, int nh_shift,
                                                   int in_stride, int in_off, float scale) {
  int idx = blockIdx.x * 256 + threadIdx.x;
  int nh = 1 << nh_shift;
  int d = idx & 127;
  int t = idx >> 7;
  int h = t & (nh - 1);
  int row = t >> nh_shift;  // b*L + l
  int l = row & (L_ - 1);
  int b = row >> 11;
  size_t ibase = (size_t)row * in_stride + in_off + h * 256 + d;
  float x1 = bf2f(in[ibase]);
  float x2 = bf2f(in[ibase + 128]);
  float f = exp2f(-(float)d * (13.287712379549449f / 128.0f));
  float ang = (float)l * f;
  float s, c;
  sincosf(ang, &s, &c);
  size_t obase = ((size_t)(b * nh + h) * L_ + l) * 256 + d;
  out[obase] = f2bf((x1 * c - x2 * s) * scale);
  out[obase + 128] = f2bf((x2 * c + x1 * s) * scale);
}

// qkvproj bf16 [B*L][2560] (V at col off 2304) -> vt bf16 [(b*256+d)][L]
__global__ __launch_bounds__(256) void vt_kernel(const u16* __restrict__ qkvproj,
                                                 u16* __restrict__ vt) {
  int idx = blockIdx.x * 256 + threadIdx.x;  // = (b*256+d)*2048 + l
  int l = idx & 2047;
  int d = (idx >> 11) & 255;
  int b = idx >> 19;
  vt[idx] = qkvproj[((size_t)b * 2048 + l) * 2560 + 2304 + d];
}

// C[M][N] = A[M][K] @ Bt[N][K]^T, bf16 in, fp32 acc, bf16 or fp32 out.
// 128x128 tile, BK=32, 4 waves 2x2; m97 global_load_lds staging;
// T1 bijective chunked XCD swizzle on the flat block index.
template <int F32OUT>
__global__ __launch_bounds__(256) void gemm_bt_kernel(const u16* __restrict__ A,
                                                      const u16* __restrict__ Bt,
                                                      void* __restrict__ Cv,
                                                      int M, int N, int K) {
  __shared__ __attribute__((aligned(16))) u16 As[128 * 32];
  __shared__ __attribute__((aligned(16))) u16 Bs[128 * 32];
  const int tid = threadIdx.x;
  const int lane = tid & 63;
  const int w = tid >> 6;
  const int wr = w >> 1, wc = w & 1;
  // XCD-aware swizzle (bijective; nwg%8==0 in all our launches)
  const int nbx = gridDim.x;
  int flat = blockIdx.y * nbx + blockIdx.x;
  int nwg = nbx * gridDim.y;
  int q8 = nwg >> 3, r8 = nwg & 7;
  int xcd = flat & 7, idx8 = flat >> 3;
  int neu = (xcd < r8 ? xcd * (q8 + 1) : r8 * (q8 + 1) + (xcd - r8) * q8) + idx8;
  const int m0 = (neu / nbx) * 128, n0 = (neu % nbx) * 128;
  const int l15 = lane & 15, l4 = lane >> 4;
  f32x4 acc[4][4] = {};
  for (int kt = 0; kt < K; kt += 32) {
#pragma unroll
    for (int i = 0; i < 2; ++i) {
      int c = tid + i * 256;
      int row = c >> 2, cin = c & 3;  // linear LDS: byte off = c*16
      gload_lds16(A + (size_t)(m0 + row) * K + kt + cin * 8,
                  (char*)As + (i * 256 + w * 64) * 16);
      gload_lds16(Bt + (size_t)(n0 + row) * K + kt + cin * 8,
                  (char*)Bs + (i * 256 + w * 64) * 16);
    }
    __syncthreads();
    short8x a[4], b[4];
#pragma unroll
    for (int m = 0; m < 4; ++m)
      a[m] = *(const short8x*)(&As[(wr * 64 + m * 16 + l15) * 32 + l4 * 8]);
#pragma unroll
    for (int n = 0; n < 4; ++n)
      b[n] = *(const short8x*)(&Bs[(wc * 64 + n * 16 + l15) * 32 + l4 * 8]);
#pragma unroll
    for (int m = 0; m < 4; ++m)
#pragma unroll
      for (int n = 0; n < 4; ++n)
        acc[m][n] = __builtin_amdgcn_mfma_f32_16x16x32_bf16(a[m], b[n], acc[m][n], 0, 0, 0);
    __syncthreads();
  }
#pragma unroll
  for (int m = 0; m < 4; ++m) {
#pragma unroll
    for (int n = 0; n < 4; ++n) {
      int gcol = n0 + wc * 64 + n * 16 + l15;
#pragma unroll
      for (int r = 0; r < 4; ++r) {
        int grow = m0 + wr * 64 + m * 16 + l4 * 4 + r;
        if (F32OUT)
          ((float*)Cv)[(size_t)grow * N + gcol] = acc[m][n][r];
        else
          ((u16*)Cv)[(size_t)grow * N + gcol] = f2bf(acc[m][n][r]);
      }
    }
  }
}

// Flash attention v7 — 4-wave blocks, 2 blocks/CU, uniform diagonal.
// qb: [B*H][L][256] (Q pre-scaled), kb: [B][L][256], vt: [B][256][L],
// attn_o: [B*L][H*256].
// grid = 512: j = 31 - (x>>4) (64-row Q-block, heavy first), bh = x&15.
// Wave w owns q-rows j*64 + w*16 .. +15 -> tq == j for ALL waves: every wave
// computes every step, mask only at t==j. nt = j+1 steps.
// LDS: K 32KB + V 32KB + Ps 8KB = 72KB -> 2 blocks/CU for any VGPR<=256.
// Single-buffered K/V (cross-block overlap hides the stage; m114 mechanism).
// T13 defer-rescale; T5 setprio around MFMA clusters.
__global__ __launch_bounds__(256) void flash_kernel(const u16* __restrict__ qb,
                                                    const u16* __restrict__ kb,
                                                    const u16* __restrict__ vt,
                                                    u16* __restrict__ attn_o) {
  __shared__ __attribute__((aligned(16))) u16 Kbuf[64 * 256];  // [k][d], read ^(k&7)<<4
  __shared__ __attribute__((aligned(16))) u16 Vbuf[256 * 64];  // [d][k], read ^(d&7)<<4
  __shared__ __attribute__((aligned(16))) u16 Ps[4 * 16 * 64]; // per-wave [q16][kv64], ^(q&7)<<4
  const int x = blockIdx.x;
  const int j = 31 - (x >> 4);        // q-block index, heavy first
  const int bh = x & 15;
  const int b = bh >> 3;
  const int h = bh & 7;
  const int tid = threadIdx.x, lane = tid & 63, w = tid >> 6;
  const int l15 = lane & 15, l4 = lane >> 4;
  const int q0 = j * 64 + w * 16;
  const int nt = j + 1;

  const u16* qrow = qb + ((size_t)(b * 8 + h) * L_ + q0 + l15) * 256;
  short8x qf[8];
#pragma unroll
  for (int kc = 0; kc < 8; ++kc)
    qf[kc] = *(const short8x*)(qrow + kc * 32 + l4 * 8);

  f32x4 o[16] = {};
  float mrow = -3e38f, srow = 0.f;    // per-lane: q-row = l15

  const u16* kbase = kb + (size_t)b * (L_ * 256);
  const u16* vbase = vt + (size_t)b * (256 * L_);

  for (int t = 0; t < nt; ++t) {
    // stage K[64][256] + V^T[256][64]: 2048 16B-chunks each, 8/thread each.
    // linear LDS chunk c holds global col-chunk (c%W)^(row&7) (involution with
    // read XOR). K: W=32; V: W=8.
#pragma unroll
    for (int i2 = 0; i2 < 8; ++i2) {
      int c = i2 * 256 + tid;
      int rk = c >> 5, cck = c & 31, jk = cck ^ (rk & 7);
      gload_lds16(kbase + (size_t)(t * 64 + rk) * 256 + jk * 8,
                  (char*)Kbuf + (i2 * 256 + w * 64) * 16);
      int rd = c >> 3, ccv = c & 7, jv = ccv ^ (rd & 7);
      gload_lds16(vbase + (size_t)rd * L_ + t * 64 + jv * 8,
                  (char*)Vbuf + (i2 * 256 + w * 64) * 16);
    }
    asm volatile("s_waitcnt vmcnt(0)" ::: "memory");
    __syncthreads();

    // S^T = K Q^T : C row = kv (n*16 + l4*4+r), col = q (l15)
    f32x4 sacc[4] = {};
    __builtin_amdgcn_s_setprio(1);
#pragma unroll
    for (int kc = 0; kc < 8; ++kc)
#pragma unroll
      for (int n = 0; n < 4; ++n) {
        int row = n * 16 + l15;
        short8x kf = *(const short8x*)((const char*)Kbuf +
            ((row * 512 + kc * 64 + l4 * 16) ^ ((row & 7) << 4)));
        sacc[n] = __builtin_amdgcn_mfma_f32_16x16x32_bf16(kf, qf[kc], sacc[n], 0, 0, 0);
      }
    __builtin_amdgcn_s_setprio(0);
    // mask + in-lane softmax for q-row l15 (lane holds 16 kv values)
    float p[4][4];
    const bool dm = (t == j);
    const int qg = q0 + l15;
    float pm = -3e38f;
#pragma unroll
    for (int n = 0; n < 4; ++n)
#pragma unroll
      for (int r = 0; r < 4; ++r) {
        int kvg = t * 64 + n * 16 + l4 * 4 + r;
        float v = sacc[n][r];
        if (dm && (kvg > qg)) v = -1e30f;
        p[n][r] = v;
        pm = fmaxf(pm, v);
      }
    pm = fmaxf(pm, __shfl_xor(pm, 16));
    pm = fmaxf(pm, __shfl_xor(pm, 32));
    // T13: skip rescale when max didn't grow past threshold (P <= e^8, safe)
    const bool defer = __all(pm <= mrow + 8.f);
    float mn, alpha;
    if (defer) {
      mn = mrow;
    } else {
      mn = fmaxf(mrow, pm);
      alpha = __expf(mrow - mn);
      mrow = mn;
    }
    float rs = 0.f;
#pragma unroll
    for (int n = 0; n < 4; ++n)
#pragma unroll
      for (int r = 0; r < 4; ++r) {
        p[n][r] = __expf(p[n][r] - mn);
        rs += p[n][r];
      }
    rs += __shfl_xor(rs, 16);
    rs += __shfl_xor(rs, 32);
    if (defer) {
      srow += rs;
    } else {
      srow = srow * alpha + rs;
      float av[4];
#pragma unroll
      for (int r = 0; r < 4; ++r)
        av[r] = __shfl(alpha, l4 * 4 + r, 16);
#pragma unroll
      for (int ff = 0; ff < 16; ++ff) {
        o[ff][0] *= av[0]; o[ff][1] *= av[1];
        o[ff][2] *= av[2]; o[ff][3] *= av[3];
      }
    }
    // P -> Ps [q=l15][kv], XOR-swizzled, packed pairs via v_cvt_pk_bf16_f32
#pragma unroll
    for (int n = 0; n < 4; ++n)
#pragma unroll
      for (int r = 0; r < 4; r += 2) {
        unsigned pk;
        asm("v_cvt_pk_bf16_f32 %0, %1, %2" : "=v"(pk) : "v"(p[n][r]), "v"(p[n][r + 1]));
        *(unsigned*)((char*)Ps + w * 2048 +
                     ((l15 * 128 + (n * 16 + l4 * 4 + r) * 2) ^ ((l15 & 7) << 4))) = pk;
      }
    asm volatile("s_waitcnt lgkmcnt(0)" ::: "memory");
    short8x paf[2];
#pragma unroll
    for (int kc2 = 0; kc2 < 2; ++kc2)
      paf[kc2] = *(const short8x*)((const char*)Ps + w * 2048 +
          ((l15 * 128 + kc2 * 64 + l4 * 16) ^ ((l15 & 7) << 4)));
    // O += P V : contraction over kv=64
    __builtin_amdgcn_s_setprio(1);
#pragma unroll
    for (int kc2 = 0; kc2 < 2; ++kc2)
#pragma unroll
      for (int ff = 0; ff < 16; ++ff) {
        int rd = ff * 16 + l15;
        short8x vf = *(const short8x*)((const char*)Vbuf +
            ((rd * 128 + kc2 * 64 + l4 * 16) ^ ((rd & 7) << 4)));
        o[ff] = __builtin_amdgcn_mfma_f32_16x16x32_bf16(paf[kc2], vf, o[ff], 0, 0, 0);
      }
    __builtin_amdgcn_s_setprio(0);
    __syncthreads();  // LDS reads done before next stage overwrites
  }
  // epilogue: srow keyed by q=l15; o rows are q=l4*4+r
  float sv[4];
#pragma unroll
  for (int r = 0; r < 4; ++r)
    sv[r] = __shfl(srow, l4 * 4 + r, 16);
#pragma unroll
  for (int r = 0; r < 4; ++r) {
    float inv = 1.0f / sv[r];
    int grow = q0 + l4 * 4 + r;
    size_t base = ((size_t)b * L_ + grow) * (size_t)(H_ * HD_) + h * 256;
#pragma unroll
    for (int ff = 0; ff < 16; ++ff)
      attn_o[base + ff * 16 + l15] = f2bf(o[ff][r] * inv);
  }
}

extern "C" void kernel_launch(void* const* d_in, const int* in_sizes, int n_in,
                              void* d_out, int out_size, void* d_ws, size_t ws_size,
                              hipStream_t stream) {
  const float* x  = (const float*)d_in[0];
  const float* Wq = (const float*)d_in[1];
  const float* Wk = (const float*)d_in[2];
  const float* Wv = (const float*)d_in[3];
  const float* Wo = (const float*)d_in[4];
  // d_in[5] = additive causal mask: semantics reproduced analytically, not read.
  float* out = (float*)d_out;
  char* ws = (char*)d_ws;
  size_t off = 0;
  auto alloc = [&](size_t bytes) {
    void* p = ws + off;
    off = (off + bytes + 255) & ~(size_t)255;
    return p;
  };
  u16* wqkv_t  = (u16*)alloc(2560ull * 2048 * 2);  // rows: 0..2047 Wq^T | 2048..2303 Wk^T | 2304..2559 Wv^T
  u16* wo_t    = (u16*)alloc(2048ull * 2048 * 2);
  u16* xbf     = (u16*)alloc(4096ull * 2048 * 2);  // reused as roped Q
  u16* qkvproj = (u16*)alloc(4096ull * 2560 * 2);  // [B*L][2560]: Q|K|V ; head reused as attn_o
  u16* kb      = (u16*)alloc(4096ull * 256 * 2);
  u16* vtb     = (u16*)alloc(4096ull * 256 * 2);
  u16* qbuf    = xbf;      // alias: x_bf dead after QKV projection
  u16* attn_o  = qkvproj;  // alias: qkvproj dead after rope/vt

  cvt_x_kernel<<<8192, 256, 0, stream>>>((const float4*)x, xbf);
  cvt_wt_kernel<<<dim3(64, 64), dim3(32, 8), 0, stream>>>(Wq, wqkv_t, 2048, 2048);
  cvt_wt_kernel<<<dim3(8, 64),  dim3(32, 8), 0, stream>>>(Wk, wqkv_t + 2048ull * 2048, 2048, 256);
  cvt_wt_kernel<<<dim3(8, 64),  dim3(32, 8), 0, stream>>>(Wv, wqkv_t + 2304ull * 2048, 2048, 256);
  cvt_wt_kernel<<<dim3(64, 64), dim3(32, 8), 0, stream>>>(Wo, wo_t, 2048, 2048);

  // fused QKV projection: M=4096, N=2560, K=2048 (grid 20x32 = 640 blocks)
  gemm_bt_kernel<0><<<dim3(20, 32), 256, 0, stream>>>(xbf, wqkv_t, qkvproj, 4096, 2560, 2048);

  rope_kernel<<<16384, 256, 0, stream>>>(qkvproj, qbuf, 3, 2560, 0, 0.0625f);  // Q (scaled)
  rope_kernel<<<2048, 256, 0, stream>>>(qkvproj, kb, 0, 2560, 2048, 1.0f);     // K
  vt_kernel<<<4096, 256, 0, stream>>>(qkvproj, vtb);

  flash_kernel<<<512, 256, 0, stream>>>(qbuf, kb, vtb, attn_o);

  gemm_bt_kernel<1><<<dim3(16, 32), 256, 0, stream>>>(attn_o, wo_t, out, 4096, 2048, 2048);
}

// Round 8
// 255.113 us; speedup vs baseline: 2.4046x; 1.0292x over previous
//
#include <hip/hip_runtime.h>

typedef unsigned short u16;
typedef __attribute__((ext_vector_type(8))) short short8x;
typedef __attribute__((ext_vector_type(4))) float f32x4;

#define B_ 2
#define L_ 2048
#define HID_ 2048
#define H_ 8
#define HD_ 256

__device__ __forceinline__ u16 f2bf(float f) {
  union { float f; unsigned u; } v; v.f = f;
  unsigned r = v.u + 0x7FFFu + ((v.u >> 16) & 1u);
  return (u16)(r >> 16);
}
__device__ __forceinline__ float bf2f(u16 u) {
  union { unsigned u; float f; } v; v.u = ((unsigned)u) << 16;
  return v.f;
}

// async global->LDS, 16B per lane. lds ptr must be the wave-uniform base;
// HW adds lane*16.
__device__ __forceinline__ void gload_lds16(const void* g, void* l) {
  __builtin_amdgcn_global_load_lds((const __attribute__((address_space(1))) unsigned*)g,
                                   (__attribute__((address_space(3))) unsigned*)l, 16, 0, 0);
}

// x fp32 -> bf16, same layout. grid = nelem/4/256
__global__ __launch_bounds__(256) void cvt_x_kernel(const float4* __restrict__ in,
                                                    u16* __restrict__ out) {
  int idx = blockIdx.x * 256 + threadIdx.x;
  float4 v = in[idx];
  u16* o = out + (size_t)idx * 4;
  o[0] = f2bf(v.x); o[1] = f2bf(v.y); o[2] = f2bf(v.z); o[3] = f2bf(v.w);
}

// W fp32 [K][N] -> Wt bf16 [N][K] (row stride K). grid (N/32, K/32), block (32,8)
__global__ __launch_bounds__(256) void cvt_wt_kernel(const float* __restrict__ W,
                                                     u16* __restrict__ Wt, int K, int N) {
  __shared__ float tile[32][33];
  int n0 = blockIdx.x * 32, k0 = blockIdx.y * 32;
  int tx = threadIdx.x, ty = threadIdx.y;
#pragma unroll
  for (int i = 0; i < 32; i += 8)
    tile[ty + i][tx] = W[(size_t)(k0 + ty + i) * N + n0 + tx];
  __syncthreads();
#pragma unroll
  for (int i = 0; i < 32; i += 8)
    Wt[(size_t)(n0 + ty + i) * K + k0 + tx] = f2bf(tile[tx][ty + i]);
}

// RoPE + head-permute + optional scale (folds 1/sqrt(HD) into Q).
__global__ __launch_bounds__(256) void rope_kernel(const u16* __restrict__ in,
                                                   u16* __restrict__ out, int nh_shift,
                                                   int in_stride, int in_off, float scale) {
  int idx = blockIdx.x * 256 + threadIdx.x;
  int nh = 1 << nh_shift;
  int d = idx & 127;
  int t = idx >> 7;
  int h = t & (nh - 1);
  int row = t >> nh_shift;  // b*L + l
  int l = row & (L_ - 1);
  int b = row >> 11;
  size_t ibase = (size_t)row * in_stride + in_off + h * 256 + d;
  float x1 = bf2f(in[ibase]);
  float x2 = bf2f(in[ibase + 128]);
  float f = exp2f(-(float)d * (13.287712379549449f / 128.0f));
  float ang = (float)l * f;
  float s, c;
  sincosf(ang, &s, &c);
  size_t obase = ((size_t)(b * nh + h) * L_ + l) * 256 + d;
  out[obase] = f2bf((x1 * c - x2 * s) * scale);
  out[obase + 128] = f2bf((x2 * c + x1 * s) * scale);
}

// qkvproj bf16 [B*L][2560] (V at col off 2304) -> vt bf16 [(b*256+d)][L]
__global__ __launch_bounds__(256) void vt_kernel(const u16* __restrict__ qkvproj,
                                                 u16* __restrict__ vt) {
  int idx = blockIdx.x * 256 + threadIdx.x;  // = (b*256+d)*2048 + l
  int l = idx & 2047;
  int d = (idx >> 11) & 255;
  int b = idx >> 19;
  vt[idx] = qkvproj[((size_t)b * 2048 + l) * 2560 + 2304 + d];
}

// C[M][N] = A[M][K] @ Bt[N][K]^T, bf16 in, fp32 acc, bf16 or fp32 out.
// 128x128 tile, BK=32, 4 waves 2x2; m97 global_load_lds staging;
// T1 bijective chunked XCD swizzle on the flat block index.
template <int F32OUT>
__global__ __launch_bounds__(256) void gemm_bt_kernel(const u16* __restrict__ A,
                                                      const u16* __restrict__ Bt,
                                                      void* __restrict__ Cv,
                                                      int M, int N, int K) {
  __shared__ __attribute__((aligned(16))) u16 As[128 * 32];
  __shared__ __attribute__((aligned(16))) u16 Bs[128 * 32];
  const int tid = threadIdx.x;
  const int lane = tid & 63;
  const int w = tid >> 6;
  const int wr = w >> 1, wc = w & 1;
  // XCD-aware swizzle (bijective; nwg%8==0 in all our launches)
  const int nbx = gridDim.x;
  int flat = blockIdx.y * nbx + blockIdx.x;
  int nwg = nbx * gridDim.y;
  int q8 = nwg >> 3, r8 = nwg & 7;
  int xcd = flat & 7, idx8 = flat >> 3;
  int neu = (xcd < r8 ? xcd * (q8 + 1) : r8 * (q8 + 1) + (xcd - r8) * q8) + idx8;
  const int m0 = (neu / nbx) * 128, n0 = (neu % nbx) * 128;
  const int l15 = lane & 15, l4 = lane >> 4;
  f32x4 acc[4][4] = {};
  for (int kt = 0; kt < K; kt += 32) {
#pragma unroll
    for (int i = 0; i < 2; ++i) {
      int c = tid + i * 256;
      int row = c >> 2, cin = c & 3;  // linear LDS: byte off = c*16
      gload_lds16(A + (size_t)(m0 + row) * K + kt + cin * 8,
                  (char*)As + (i * 256 + w * 64) * 16);
      gload_lds16(Bt + (size_t)(n0 + row) * K + kt + cin * 8,
                  (char*)Bs + (i * 256 + w * 64) * 16);
    }
    __syncthreads();
    short8x a[4], b[4];
#pragma unroll
    for (int m = 0; m < 4; ++m)
      a[m] = *(const short8x*)(&As[(wr * 64 + m * 16 + l15) * 32 + l4 * 8]);
#pragma unroll
    for (int n = 0; n < 4; ++n)
      b[n] = *(const short8x*)(&Bs[(wc * 64 + n * 16 + l15) * 32 + l4 * 8]);
#pragma unroll
    for (int m = 0; m < 4; ++m)
#pragma unroll
      for (int n = 0; n < 4; ++n)
        acc[m][n] = __builtin_amdgcn_mfma_f32_16x16x32_bf16(a[m], b[n], acc[m][n], 0, 0, 0);
    __syncthreads();
  }
#pragma unroll
  for (int m = 0; m < 4; ++m) {
#pragma unroll
    for (int n = 0; n < 4; ++n) {
      int gcol = n0 + wc * 64 + n * 16 + l15;
#pragma unroll
      for (int r = 0; r < 4; ++r) {
        int grow = m0 + wr * 64 + m * 16 + l4 * 4 + r;
        if (F32OUT)
          ((float*)Cv)[(size_t)grow * N + gcol] = acc[m][n][r];
        else
          ((u16*)Cv)[(size_t)grow * N + gcol] = f2bf(acc[m][n][r]);
      }
    }
  }
}

// Flash attention v8 — v7 + double-buffered K/V with prefetch-ahead.
// qb: [B*H][L][256] (Q pre-scaled), kb: [B][L][256], vt: [B][256][L],
// attn_o: [B*L][H*256].
// grid = 512: j = 31 - (x>>4) (64-row Q-block, heavy first), bh = x&15.
// Wave w owns q-rows j*64 + w*16 .. +15 -> tq == j for ALL waves.
// LDS: K 2x32KB + V 2x32KB + Ps 8KB = 136KB -> 1 block/CU; the dbuf prefetch
// (STAGE(t+1) issued before computing tile t) replaces cross-block overlap:
// one vmcnt(0)+barrier per step, stage latency hidden under QK/softmax/PV.
__global__ __launch_bounds__(256) void flash_kernel(const u16* __restrict__ qb,
                                                    const u16* __restrict__ kb,
                                                    const u16* __restrict__ vt,
                                                    u16* __restrict__ attn_o) {
  __shared__ __attribute__((aligned(16))) u16 Kbuf[2][64 * 256];  // [k][d], read ^(k&7)<<4
  __shared__ __attribute__((aligned(16))) u16 Vbuf[2][256 * 64];  // [d][k], read ^(d&7)<<4
  __shared__ __attribute__((aligned(16))) u16 Ps[4 * 16 * 64];    // per-wave [q16][kv64], ^(q&7)<<4
  const int x = blockIdx.x;
  const int j = 31 - (x >> 4);        // q-block index, heavy first
  const int bh = x & 15;
  const int b = bh >> 3;
  const int h = bh & 7;
  const int tid = threadIdx.x, lane = tid & 63, w = tid >> 6;
  const int l15 = lane & 15, l4 = lane >> 4;
  const int q0 = j * 64 + w * 16;
  const int nt = j + 1;

  const u16* qrow = qb + ((size_t)(b * 8 + h) * L_ + q0 + l15) * 256;
  short8x qf[8];
#pragma unroll
  for (int kc = 0; kc < 8; ++kc)
    qf[kc] = *(const short8x*)(qrow + kc * 32 + l4 * 8);

  f32x4 o[16] = {};
  float mrow = -3e38f, srow = 0.f;    // per-lane: q-row = l15

  const u16* kbase = kb + (size_t)b * (L_ * 256);
  const u16* vbase = vt + (size_t)b * (256 * L_);

  // stage K[64][256] + V^T[256][64] into buffer s: 2048 16B-chunks each,
  // 8/thread each. linear LDS chunk c holds global col-chunk (c%W)^(row&7)
  // (involution with read XOR). K: W=32; V: W=8.
#define STAGE(t, s)                                                            \
  {                                                                            \
    _Pragma("unroll") for (int i2 = 0; i2 < 8; ++i2) {                         \
      int c = i2 * 256 + tid;                                                  \
      int rk = c >> 5, cck = c & 31, jk = cck ^ (rk & 7);                      \
      gload_lds16(kbase + (size_t)((t) * 64 + rk) * 256 + jk * 8,              \
                  (char*)&Kbuf[s][0] + (i2 * 256 + w * 64) * 16);              \
      int rd = c >> 3, ccv = c & 7, jv = ccv ^ (rd & 7);                       \
      gload_lds16(vbase + (size_t)rd * L_ + (t) * 64 + jv * 8,                 \
                  (char*)&Vbuf[s][0] + (i2 * 256 + w * 64) * 16);              \
    }                                                                          \
  }

  STAGE(0, 0);
  asm volatile("s_waitcnt vmcnt(0)" ::: "memory");
  __syncthreads();

  for (int t = 0; t < nt; ++t) {
    if (t + 1 < nt) STAGE(t + 1, (t + 1) & 1);  // prefetch lands under compute
    const char* Kb = (const char*)&Kbuf[t & 1][0];
    const char* Vb = (const char*)&Vbuf[t & 1][0];

    // S^T = K Q^T : C row = kv (n*16 + l4*4+r), col = q (l15)
    f32x4 sacc[4] = {};
    __builtin_amdgcn_s_setprio(1);
#pragma unroll
    for (int kc = 0; kc < 8; ++kc)
#pragma unroll
      for (int n = 0; n < 4; ++n) {
        int row = n * 16 + l15;
        short8x kf = *(const short8x*)(Kb +
            ((row * 512 + kc * 64 + l4 * 16) ^ ((row & 7) << 4)));
        sacc[n] = __builtin_amdgcn_mfma_f32_16x16x32_bf16(kf, qf[kc], sacc[n], 0, 0, 0);
      }
    __builtin_amdgcn_s_setprio(0);
    // mask + in-lane softmax for q-row l15 (lane holds 16 kv values)
    float p[4][4];
    const bool dm = (t == j);
    const int qg = q0 + l15;
    float pm = -3e38f;
#pragma unroll
    for (int n = 0; n < 4; ++n)
#pragma unroll
      for (int r = 0; r < 4; ++r) {
        int kvg = t * 64 + n * 16 + l4 * 4 + r;
        float v = sacc[n][r];
        if (dm && (kvg > qg)) v = -1e30f;
        p[n][r] = v;
        pm = fmaxf(pm, v);
      }
    pm = fmaxf(pm, __shfl_xor(pm, 16));
    pm = fmaxf(pm, __shfl_xor(pm, 32));
    // T13: skip rescale when max didn't grow past threshold (P <= e^8, safe)
    const bool defer = __all(pm <= mrow + 8.f);
    float mn, alpha;
    if (defer) {
      mn = mrow;
    } else {
      mn = fmaxf(mrow, pm);
      alpha = __expf(mrow - mn);
      mrow = mn;
    }
    float rs = 0.f;
#pragma unroll
    for (int n = 0; n < 4; ++n)
#pragma unroll
      for (int r = 0; r < 4; ++r) {
        p[n][r] = __expf(p[n][r] - mn);
        rs += p[n][r];
      }
    rs += __shfl_xor(rs, 16);
    rs += __shfl_xor(rs, 32);
    if (defer) {
      srow += rs;
    } else {
      srow = srow * alpha + rs;
      float av[4];
#pragma unroll
      for (int r = 0; r < 4; ++r)
        av[r] = __shfl(alpha, l4 * 4 + r, 16);
#pragma unroll
      for (int ff = 0; ff < 16; ++ff) {
        o[ff][0] *= av[0]; o[ff][1] *= av[1];
        o[ff][2] *= av[2]; o[ff][3] *= av[3];
      }
    }
    // P -> Ps [q=l15][kv], XOR-swizzled, packed pairs via v_cvt_pk_bf16_f32
#pragma unroll
    for (int n = 0; n < 4; ++n)
#pragma unroll
      for (int r = 0; r < 4; r += 2) {
        unsigned pk;
        asm("v_cvt_pk_bf16_f32 %0, %1, %2" : "=v"(pk) : "v"(p[n][r]), "v"(p[n][r + 1]));
        *(unsigned*)((char*)Ps + w * 2048 +
                     ((l15 * 128 + (n * 16 + l4 * 4 + r) * 2) ^ ((l15 & 7) << 4))) = pk;
      }
    asm volatile("s_waitcnt lgkmcnt(0)" ::: "memory");
    short8x paf[2];
#pragma unroll
    for (int kc2 = 0; kc2 < 2; ++kc2)
      paf[kc2] = *(const short8x*)((const char*)Ps + w * 2048 +
          ((l15 * 128 + kc2 * 64 + l4 * 16) ^ ((l15 & 7) << 4)));
    // O += P V : contraction over kv=64
    __builtin_amdgcn_s_setprio(1);
#pragma unroll
    for (int kc2 = 0; kc2 < 2; ++kc2)
#pragma unroll
      for (int ff = 0; ff < 16; ++ff) {
        int rd = ff * 16 + l15;
        short8x vf = *(const short8x*)(Vb +
            ((rd * 128 + kc2 * 64 + l4 * 16) ^ ((rd & 7) << 4)));
        o[ff] = __builtin_amdgcn_mfma_f32_16x16x32_bf16(paf[kc2], vf, o[ff], 0, 0, 0);
      }
    __builtin_amdgcn_s_setprio(0);
    // next tile's DMA (issued at step start) complete + all waves done reading
    asm volatile("s_waitcnt vmcnt(0)" ::: "memory");
    __syncthreads();
  }
  // epilogue: srow keyed by q=l15; o rows are q=l4*4+r
  float sv[4];
#pragma unroll
  for (int r = 0; r < 4; ++r)
    sv[r] = __shfl(srow, l4 * 4 + r, 16);
#pragma unroll
  for (int r = 0; r < 4; ++r) {
    float inv = 1.0f / sv[r];
    int grow = q0 + l4 * 4 + r;
    size_t base = ((size_t)b * L_ + grow) * (size_t)(H_ * HD_) + h * 256;
#pragma unroll
    for (int ff = 0; ff < 16; ++ff)
      attn_o[base + ff * 16 + l15] = f2bf(o[ff][r] * inv);
  }
#undef STAGE
}

extern "C" void kernel_launch(void* const* d_in, const int* in_sizes, int n_in,
                              void* d_out, int out_size, void* d_ws, size_t ws_size,
                              hipStream_t stream) {
  const float* x  = (const float*)d_in[0];
  const float* Wq = (const float*)d_in[1];
  const float* Wk = (const float*)d_in[2];
  const float* Wv = (const float*)d_in[3];
  const float* Wo = (const float*)d_in[4];
  // d_in[5] = additive causal mask: semantics reproduced analytically, not read.
  float* out = (float*)d_out;
  char* ws = (char*)d_ws;
  size_t off = 0;
  auto alloc = [&](size_t bytes) {
    void* p = ws + off;
    off = (off + bytes + 255) & ~(size_t)255;
    return p;
  };
  u16* wqkv_t  = (u16*)alloc(2560ull * 2048 * 2);  // rows: 0..2047 Wq^T | 2048..2303 Wk^T | 2304..2559 Wv^T
  u16* wo_t    = (u16*)alloc(2048ull * 2048 * 2);
  u16* xbf     = (u16*)alloc(4096ull * 2048 * 2);  // reused as roped Q
  u16* qkvproj = (u16*)alloc(4096ull * 2560 * 2);  // [B*L][2560]: Q|K|V ; head reused as attn_o
  u16* kb      = (u16*)alloc(4096ull * 256 * 2);
  u16* vtb     = (u16*)alloc(4096ull * 256 * 2);
  u16* qbuf    = xbf;      // alias: x_bf dead after QKV projection
  u16* attn_o  = qkvproj;  // alias: qkvproj dead after rope/vt

  cvt_x_kernel<<<8192, 256, 0, stream>>>((const float4*)x, xbf);
  cvt_wt_kernel<<<dim3(64, 64), dim3(32, 8), 0, stream>>>(Wq, wqkv_t, 2048, 2048);
  cvt_wt_kernel<<<dim3(8, 64),  dim3(32, 8), 0, stream>>>(Wk, wqkv_t + 2048ull * 2048, 2048, 256);
  cvt_wt_kernel<<<dim3(8, 64),  dim3(32, 8), 0, stream>>>(Wv, wqkv_t + 2304ull * 2048, 2048, 256);
  cvt_wt_kernel<<<dim3(64, 64), dim3(32, 8), 0, stream>>>(Wo, wo_t, 2048, 2048);

  // fused QKV projection: M=4096, N=2560, K=2048 (grid 20x32 = 640 blocks)
  gemm_bt_kernel<0><<<dim3(20, 32), 256, 0, stream>>>(xbf, wqkv_t, qkvproj, 4096, 2560, 2048);

  rope_kernel<<<16384, 256, 0, stream>>>(qkvproj, qbuf, 3, 2560, 0, 0.0625f);  // Q (scaled)
  rope_kernel<<<2048, 256, 0, stream>>>(qkvproj, kb, 0, 2560, 2048, 1.0f);     // K
  vt_kernel<<<4096, 256, 0, stream>>>(qkvproj, vtb);

  flash_kernel<<<512, 256, 0, stream>>>(qbuf, kb, vtb, attn_o);

  gemm_bt_kernel<1><<<dim3(16, 32), 256, 0, stream>>>(attn_o, wo_t, out, 4096, 2048, 2048);
}